// Round 3
// baseline (6469.657 us; speedup 1.0000x reference)
//
#include <hip/hip_runtime.h>
#include <hip/hip_bf16.h>

#define NN 50000
#define NE 600000
#define DD 128
#define ITERS 3
#define GR 32   // rows per GEMM block

typedef __hip_bfloat16  bf16;

// ---------------- runtime dtype sniffer ----------------
// flags[0] = 1 if float inputs are fp32, 0 if bf16-packed
// flags[1] = 1 if adjacency is int64, 0 if int32
__global__ void k_sniff(const unsigned* __restrict__ w,
                        const unsigned* __restrict__ adj,
                        int* __restrict__ flags) {
    __shared__ int cnt[2];
    int tid = threadIdx.x;
    if (tid < 2) cnt[tid] = 0;
    __syncthreads();
    int c0 = 0, c1 = 0;
    // W_emb words: low 16 bits are a plausible bf16 iff inputs are bf16-packed
    for (int i = tid; i < 512; i += 256) {
        unsigned e = (w[i] >> 7) & 0xFFu;      // exponent byte of low-half bf16
        c0 += (e >= 0x60u && e <= 0x85u) ? 1 : 0;
    }
    // adjacency: odd words are all-zero high words iff int64
    for (int i = tid; i < 512; i += 256) {
        c1 += (adj[2 * i + 1] == 0u) ? 1 : 0;
    }
    atomicAdd(&cnt[0], c0);
    atomicAdd(&cnt[1], c1);
    __syncthreads();
    if (tid == 0) {
        flags[0] = (cnt[0] >= 256) ? 0 : 1;    // many plausible-bf16 halves -> bf16
        flags[1] = (cnt[1] >= 256) ? 1 : 0;    // many zero odd-words -> int64
    }
}

__device__ __forceinline__ float ld_in(const void* p, int idx, int f32) {
    return f32 ? ((const float*)p)[idx]
               : __bfloat162float(((const bf16*)p)[idx]);
}

__device__ __forceinline__ void ld_edge(const int* adj, int e, int i64, int& s, int& d) {
    if (i64) { s = adj[4 * e]; d = adj[4 * e + 2]; }   // low words (little-endian)
    else     { s = adj[2 * e]; d = adj[2 * e + 1]; }
}

// ---------------- degree ----------------
__global__ void k_degree(const int* __restrict__ adj, const int* __restrict__ flags,
                         int* __restrict__ deg) {
    int e = blockIdx.x * blockDim.x + threadIdx.x;
    if (e < NE) {
        int s, d;
        ld_edge(adj, e, flags[1], s, d);
        if ((unsigned)s < NN) atomicAdd(&deg[s], 1);
        if ((unsigned)d < NN) atomicAdd(&deg[d], 1);
    }
}

__global__ void k_invdenom(const int* __restrict__ deg, float* __restrict__ inv) {
    int n = blockIdx.x * blockDim.x + threadIdx.x;
    if (n < NN) inv[n] = 1.0f / ((float)deg[n] + 1.0f);
}

// ---------------- GEMM 1: h = relu(X @ W_emb + b) -> d_out (dtype per flag) ----------------
__launch_bounds__(256, 2)
__global__ void k_gemm_emb(const void* __restrict__ Xp, const void* __restrict__ Wp,
                           const void* __restrict__ Bp, void* __restrict__ Hp,
                           const int* __restrict__ flags) {
    __shared__ float ws[DD * DD];   // 64 KB
    __shared__ float xs[GR * DD];   // 16 KB
    const int f32  = flags[0];
    const int tid  = threadIdx.x;
    const int row0 = blockIdx.x * GR;

    for (int i = tid; i < DD * DD; i += 256) ws[i] = ld_in(Wp, i, f32);
    for (int i = tid; i < GR * DD; i += 256) {
        int r = row0 + (i >> 7);
        xs[i] = (r < NN) ? ld_in(Xp, r * DD + (i & 127), f32) : 0.0f;
    }
    __syncthreads();

    const int cq = (tid & 31) << 2;
    const int rg = tid >> 5;
    float acc[4][4];
#pragma unroll
    for (int r = 0; r < 4; r++)
#pragma unroll
        for (int c = 0; c < 4; c++) acc[r][c] = 0.0f;

    for (int k = 0; k < DD; k += 4) {
        float4 xv[4];
#pragma unroll
        for (int r = 0; r < 4; r++)
            xv[r] = *(const float4*)&xs[(rg + 8 * r) * DD + k];
#pragma unroll
        for (int kk = 0; kk < 4; kk++) {
            float4 w = *(const float4*)&ws[(k + kk) * DD + cq];
#pragma unroll
            for (int r = 0; r < 4; r++) {
                float xc = ((const float*)&xv[r])[kk];
                acc[r][0] += xc * w.x;
                acc[r][1] += xc * w.y;
                acc[r][2] += xc * w.z;
                acc[r][3] += xc * w.w;
            }
        }
    }

    float b0 = ld_in(Bp, cq, f32),     b1 = ld_in(Bp, cq + 1, f32);
    float b2 = ld_in(Bp, cq + 2, f32), b3 = ld_in(Bp, cq + 3, f32);
#pragma unroll
    for (int r = 0; r < 4; r++) {
        int row = row0 + rg + 8 * r;
        if (row < NN) {
            float o0 = fmaxf(acc[r][0] + b0, 0.0f);
            float o1 = fmaxf(acc[r][1] + b1, 0.0f);
            float o2 = fmaxf(acc[r][2] + b2, 0.0f);
            float o3 = fmaxf(acc[r][3] + b3, 0.0f);
            if (f32) {
                float4 o = {o0, o1, o2, o3};
                *(float4*)&((float*)Hp)[row * DD + cq] = o;
            } else {
                bf16* o = &((bf16*)Hp)[row * DD + cq];
                o[0] = __float2bfloat16(o0); o[1] = __float2bfloat16(o1);
                o[2] = __float2bfloat16(o2); o[3] = __float2bfloat16(o3);
            }
        }
    }
}

// ---------------- GEMM 2: h = sigmoid(((h+agg)*inv) @ W_upd + b), in-place on d_out ----------------
__launch_bounds__(256, 2)
__global__ void k_gemm_upd(void* __restrict__ Hp, const float* __restrict__ AGG,
                           const float* __restrict__ INV,
                           const void* __restrict__ Wp, const void* __restrict__ Bp,
                           const int* __restrict__ flags) {
    __shared__ float ws[DD * DD];
    __shared__ float xs[GR * DD];
    const int f32  = flags[0];
    const int tid  = threadIdx.x;
    const int row0 = blockIdx.x * GR;

    for (int i = tid; i < DD * DD; i += 256) ws[i] = ld_in(Wp, i, f32);
    for (int i = tid; i < GR * DD; i += 256) {
        int r = row0 + (i >> 7);
        if (r < NN) {
            int g = r * DD + (i & 127);
            float h = f32 ? ((const float*)Hp)[g]
                          : __bfloat162float(((const bf16*)Hp)[g]);
            xs[i] = (h + AGG[g]) * INV[r];
        } else {
            xs[i] = 0.0f;
        }
    }
    __syncthreads();

    const int cq = (tid & 31) << 2;
    const int rg = tid >> 5;
    float acc[4][4];
#pragma unroll
    for (int r = 0; r < 4; r++)
#pragma unroll
        for (int c = 0; c < 4; c++) acc[r][c] = 0.0f;

    for (int k = 0; k < DD; k += 4) {
        float4 xv[4];
#pragma unroll
        for (int r = 0; r < 4; r++)
            xv[r] = *(const float4*)&xs[(rg + 8 * r) * DD + k];
#pragma unroll
        for (int kk = 0; kk < 4; kk++) {
            float4 w = *(const float4*)&ws[(k + kk) * DD + cq];
#pragma unroll
            for (int r = 0; r < 4; r++) {
                float xc = ((const float*)&xv[r])[kk];
                acc[r][0] += xc * w.x;
                acc[r][1] += xc * w.y;
                acc[r][2] += xc * w.z;
                acc[r][3] += xc * w.w;
            }
        }
    }

    float b0 = ld_in(Bp, cq, f32),     b1 = ld_in(Bp, cq + 1, f32);
    float b2 = ld_in(Bp, cq + 2, f32), b3 = ld_in(Bp, cq + 3, f32);
#pragma unroll
    for (int r = 0; r < 4; r++) {
        int row = row0 + rg + 8 * r;
        if (row < NN) {
            float o0 = 1.0f / (1.0f + __expf(-(acc[r][0] + b0)));
            float o1 = 1.0f / (1.0f + __expf(-(acc[r][1] + b1)));
            float o2 = 1.0f / (1.0f + __expf(-(acc[r][2] + b2)));
            float o3 = 1.0f / (1.0f + __expf(-(acc[r][3] + b3)));
            if (f32) {
                float4 o = {o0, o1, o2, o3};
                *(float4*)&((float*)Hp)[row * DD + cq] = o;
            } else {
                bf16* o = &((bf16*)Hp)[row * DD + cq];
                o[0] = __float2bfloat16(o0); o[1] = __float2bfloat16(o1);
                o[2] = __float2bfloat16(o2); o[3] = __float2bfloat16(o3);
            }
        }
    }
}

// ---------------- bidirectional scatter-add: agg[s]+=h[d], agg[d]+=h[s] ----------------
__launch_bounds__(256)
__global__ void k_scatter(const void* __restrict__ Hp, const int* __restrict__ adj,
                          const int* __restrict__ flags, float* __restrict__ AGG) {
    int t = blockIdx.x * 256 + threadIdx.x;
    int e = t >> 5;                 // 32 threads per edge
    if (e >= NE) return;
    int c = (t & 31) << 2;          // 4 channels per thread
    int s, d;
    ld_edge(adj, e, flags[1], s, d);
    if ((unsigned)s >= NN || (unsigned)d >= NN) return;
    const int f32 = flags[0];
    float hs0, hs1, hs2, hs3, hd0, hd1, hd2, hd3;
    if (f32) {
        float4 hs = *(const float4*)&((const float*)Hp)[s * DD + c];
        float4 hd = *(const float4*)&((const float*)Hp)[d * DD + c];
        hs0 = hs.x; hs1 = hs.y; hs2 = hs.z; hs3 = hs.w;
        hd0 = hd.x; hd1 = hd.y; hd2 = hd.z; hd3 = hd.w;
    } else {
        const bf16* hb = (const bf16*)Hp;
        hs0 = __bfloat162float(hb[s * DD + c]);     hs1 = __bfloat162float(hb[s * DD + c + 1]);
        hs2 = __bfloat162float(hb[s * DD + c + 2]); hs3 = __bfloat162float(hb[s * DD + c + 3]);
        hd0 = __bfloat162float(hb[d * DD + c]);     hd1 = __bfloat162float(hb[d * DD + c + 1]);
        hd2 = __bfloat162float(hb[d * DD + c + 2]); hd3 = __bfloat162float(hb[d * DD + c + 3]);
    }
    float* as = &AGG[s * DD + c];
    float* ad = &AGG[d * DD + c];
    unsafeAtomicAdd(as + 0, hd0);
    unsafeAtomicAdd(as + 1, hd1);
    unsafeAtomicAdd(as + 2, hd2);
    unsafeAtomicAdd(as + 3, hd3);
    unsafeAtomicAdd(ad + 0, hs0);
    unsafeAtomicAdd(ad + 1, hs1);
    unsafeAtomicAdd(ad + 2, hs2);
    unsafeAtomicAdd(ad + 3, hs3);
}

extern "C" void kernel_launch(void* const* d_in, const int* in_sizes, int n_in,
                              void* d_out, int out_size, void* d_ws, size_t ws_size,
                              hipStream_t stream) {
    const void* X  = d_in[0];
    const void* We = d_in[1];
    const void* be = d_in[2];
    const void* Wu = d_in[3];
    const void* bu = d_in[4];
    const int* adj = (const int*)d_in[5];

    // ws layout: FLAGS(64B) | DEG(200KB) | INV(200KB) | AGG(25.6MB)  => 26.0 MB
    int*   FLAGS = (int*)d_ws;
    int*   DEG   = (int*)((char*)d_ws + 64);
    float* INV   = (float*)(DEG + NN);
    float* AGG   = (float*)(INV + NN);

    k_sniff<<<1, 256, 0, stream>>>((const unsigned*)We, (const unsigned*)adj, FLAGS);
    hipMemsetAsync(DEG, 0, NN * sizeof(int), stream);
    k_degree<<<(NE + 255) / 256, 256, 0, stream>>>(adj, FLAGS, DEG);
    k_invdenom<<<(NN + 255) / 256, 256, 0, stream>>>(DEG, INV);
    k_gemm_emb<<<(NN + GR - 1) / GR, 256, 0, stream>>>(X, We, be, d_out, FLAGS);

    for (int it = 0; it < ITERS; ++it) {
        hipMemsetAsync(AGG, 0, (size_t)NN * DD * sizeof(float), stream);
        k_scatter<<<(NE * 32) / 256, 256, 0, stream>>>(d_out, adj, FLAGS, AGG);
        k_gemm_upd<<<(NN + GR - 1) / GR, 256, 0, stream>>>(d_out, AGG, INV, Wu, bu, FLAGS);
    }
}

// Round 4
// 868.934 us; speedup vs baseline: 7.4455x; 7.4455x over previous
//
#include <hip/hip_runtime.h>
#include <hip/hip_bf16.h>

#define NN 50000
#define NE 600000
#define DD 128
#define ITERS 3
#define GR 32   // rows per GEMM block

typedef __hip_bfloat16  bf16;
typedef __hip_bfloat162 bf162;

// ---------------- runtime dtype sniffer ----------------
// flags[0] = 1 if float inputs are fp32, 0 if bf16-packed
// flags[1] = 1 if adjacency is int64, 0 if int32
__global__ void k_sniff(const unsigned* __restrict__ w,
                        const unsigned* __restrict__ adj,
                        int* __restrict__ flags) {
    __shared__ int cnt[2];
    int tid = threadIdx.x;
    if (tid < 2) cnt[tid] = 0;
    __syncthreads();
    int c0 = 0, c1 = 0;
    for (int i = tid; i < 512; i += 256) {
        unsigned e = (w[i] >> 7) & 0xFFu;      // exponent byte of low-half bf16
        c0 += (e >= 0x60u && e <= 0x85u) ? 1 : 0;
    }
    for (int i = tid; i < 512; i += 256) {
        c1 += (adj[2 * i + 1] == 0u) ? 1 : 0;  // int64 high words are zero
    }
    atomicAdd(&cnt[0], c0);
    atomicAdd(&cnt[1], c1);
    __syncthreads();
    if (tid == 0) {
        flags[0] = (cnt[0] >= 256) ? 0 : 1;
        flags[1] = (cnt[1] >= 256) ? 1 : 0;
    }
}

__device__ __forceinline__ float ld_in(const void* p, int idx, int f32) {
    return f32 ? ((const float*)p)[idx]
               : __bfloat162float(((const bf16*)p)[idx]);
}

__device__ __forceinline__ void ld_edge(const int* adj, int e, int i64, int& s, int& d) {
    if (i64) { s = adj[4 * e]; d = adj[4 * e + 2]; }
    else     { s = adj[2 * e]; d = adj[2 * e + 1]; }
}

// ---------------- CSR build ----------------
__global__ void k_degree(const int* __restrict__ adj, const int* __restrict__ flags,
                         int* __restrict__ deg) {
    int e = blockIdx.x * blockDim.x + threadIdx.x;
    if (e < NE) {
        int s, d;
        ld_edge(adj, e, flags[1], s, d);
        if ((unsigned)s < NN && (unsigned)d < NN) {
            atomicAdd(&deg[s], 1);
            atomicAdd(&deg[d], 1);
        }
    }
}

// single-block inclusive scan over deg -> rows (exclusive starts), cur = copy of starts
__global__ void k_scan(const int* __restrict__ deg, int* __restrict__ rows,
                       int* __restrict__ cur) {
    __shared__ int sh[1024];
    __shared__ int carry_s;
    const int tid = threadIdx.x;
    if (tid == 0) { carry_s = 0; rows[0] = 0; }
    __syncthreads();
    for (int base = 0; base < NN; base += 1024) {
        int i = base + tid;
        int v = (i < NN) ? deg[i] : 0;
        sh[tid] = v;
        __syncthreads();
        for (int off = 1; off < 1024; off <<= 1) {
            int t = (tid >= off) ? sh[tid - off] : 0;
            __syncthreads();
            sh[tid] += t;
            __syncthreads();
        }
        int incl = sh[tid];
        int c = carry_s;
        __syncthreads();
        if (i < NN) { rows[i + 1] = c + incl; cur[i] = c + incl - v; }
        if (tid == 1023) carry_s = c + sh[1023];
        __syncthreads();
    }
}

__global__ void k_fill(const int* __restrict__ adj, const int* __restrict__ flags,
                       int* __restrict__ cur, unsigned short* __restrict__ nbr) {
    int e = blockIdx.x * blockDim.x + threadIdx.x;
    if (e < NE) {
        int s, d;
        ld_edge(adj, e, flags[1], s, d);
        if ((unsigned)s < NN && (unsigned)d < NN) {
            int p = atomicAdd(&cur[s], 1);
            nbr[p] = (unsigned short)d;
            int q = atomicAdd(&cur[d], 1);
            nbr[q] = (unsigned short)s;
        }
    }
}

// ---------------- gather: XBUF[row] = (h[row] + sum_nbr h) / (deg+1) ----------------
__device__ __forceinline__ float2 ldh2(const void* p, int n, int lane, int f32) {
    if (f32) return ((const float2*)p)[n * 64 + lane];
    bf162 v = ((const bf162*)p)[n * 64 + lane];
    return make_float2(__bfloat162float(v.x), __bfloat162float(v.y));
}

__launch_bounds__(256)
__global__ void k_gather(const void* __restrict__ Hp, const int* __restrict__ rows,
                         const unsigned short* __restrict__ nbr,
                         void* __restrict__ XB, const int* __restrict__ flags,
                         int xb32) {
    const int gid  = blockIdx.x * 256 + threadIdx.x;
    const int row  = gid >> 6;              // one wave per node
    const int lane = threadIdx.x & 63;      // 2 channels per lane
    if (row >= NN) return;
    const int f32 = flags[0];
    float2 a = ldh2(Hp, row, lane, f32);
    const int st = rows[row], en = rows[row + 1];
    int j = st;
    for (; j + 4 <= en; j += 4) {
        int n0 = nbr[j], n1 = nbr[j + 1], n2 = nbr[j + 2], n3 = nbr[j + 3];
        float2 a0 = ldh2(Hp, n0, lane, f32);
        float2 a1 = ldh2(Hp, n1, lane, f32);
        float2 a2 = ldh2(Hp, n2, lane, f32);
        float2 a3 = ldh2(Hp, n3, lane, f32);
        a.x += (a0.x + a1.x) + (a2.x + a3.x);
        a.y += (a0.y + a1.y) + (a2.y + a3.y);
    }
    for (; j < en; ++j) {
        float2 av = ldh2(Hp, nbr[j], lane, f32);
        a.x += av.x; a.y += av.y;
    }
    float inv = 1.0f / (float)(en - st + 1);
    a.x *= inv; a.y *= inv;
    if (xb32) {
        ((float2*)XB)[row * 64 + lane] = a;
    } else {
        bf162 v;
        v.x = __float2bfloat16(a.x);
        v.y = __float2bfloat16(a.y);
        ((bf162*)XB)[row * 64 + lane] = v;
    }
}

// ---------------- GEMM 1: h = relu(X @ W_emb + b) -> d_out ----------------
__launch_bounds__(256, 2)
__global__ void k_gemm_emb(const void* __restrict__ Xp, const void* __restrict__ Wp,
                           const void* __restrict__ Bp, void* __restrict__ Hp,
                           const int* __restrict__ flags) {
    __shared__ float ws[DD * DD];
    __shared__ float xs[GR * DD];
    const int f32  = flags[0];
    const int tid  = threadIdx.x;
    const int row0 = blockIdx.x * GR;

    for (int i = tid; i < DD * DD; i += 256) ws[i] = ld_in(Wp, i, f32);
    for (int i = tid; i < GR * DD; i += 256) {
        int r = row0 + (i >> 7);
        xs[i] = (r < NN) ? ld_in(Xp, r * DD + (i & 127), f32) : 0.0f;
    }
    __syncthreads();

    const int cq = (tid & 31) << 2;
    const int rg = tid >> 5;
    float acc[4][4];
#pragma unroll
    for (int r = 0; r < 4; r++)
#pragma unroll
        for (int c = 0; c < 4; c++) acc[r][c] = 0.0f;

    for (int k = 0; k < DD; k += 4) {
        float4 xv[4];
#pragma unroll
        for (int r = 0; r < 4; r++)
            xv[r] = *(const float4*)&xs[(rg + 8 * r) * DD + k];
#pragma unroll
        for (int kk = 0; kk < 4; kk++) {
            float4 w = *(const float4*)&ws[(k + kk) * DD + cq];
#pragma unroll
            for (int r = 0; r < 4; r++) {
                float xc = ((const float*)&xv[r])[kk];
                acc[r][0] += xc * w.x;
                acc[r][1] += xc * w.y;
                acc[r][2] += xc * w.z;
                acc[r][3] += xc * w.w;
            }
        }
    }

    float b0 = ld_in(Bp, cq, f32),     b1 = ld_in(Bp, cq + 1, f32);
    float b2 = ld_in(Bp, cq + 2, f32), b3 = ld_in(Bp, cq + 3, f32);
#pragma unroll
    for (int r = 0; r < 4; r++) {
        int row = row0 + rg + 8 * r;
        if (row < NN) {
            float o0 = fmaxf(acc[r][0] + b0, 0.0f);
            float o1 = fmaxf(acc[r][1] + b1, 0.0f);
            float o2 = fmaxf(acc[r][2] + b2, 0.0f);
            float o3 = fmaxf(acc[r][3] + b3, 0.0f);
            if (f32) {
                float4 o = {o0, o1, o2, o3};
                *(float4*)&((float*)Hp)[row * DD + cq] = o;
            } else {
                bf16* o = &((bf16*)Hp)[row * DD + cq];
                o[0] = __float2bfloat16(o0); o[1] = __float2bfloat16(o1);
                o[2] = __float2bfloat16(o2); o[3] = __float2bfloat16(o3);
            }
        }
    }
}

// ---------------- GEMM 2: h = sigmoid(XBUF @ W_upd + b) -> d_out in place ----------------
__launch_bounds__(256, 2)
__global__ void k_gemm_upd(void* __restrict__ Hp, const void* __restrict__ XB,
                           const void* __restrict__ Wp, const void* __restrict__ Bp,
                           const int* __restrict__ flags, int xb32) {
    __shared__ float ws[DD * DD];
    __shared__ float xs[GR * DD];
    const int f32  = flags[0];
    const int tid  = threadIdx.x;
    const int row0 = blockIdx.x * GR;

    for (int i = tid; i < DD * DD; i += 256) ws[i] = ld_in(Wp, i, f32);
    for (int i = tid; i < GR * DD; i += 256) {
        int r = row0 + (i >> 7);
        xs[i] = (r < NN) ? ld_in(XB, r * DD + (i & 127), xb32) : 0.0f;
    }
    __syncthreads();

    const int cq = (tid & 31) << 2;
    const int rg = tid >> 5;
    float acc[4][4];
#pragma unroll
    for (int r = 0; r < 4; r++)
#pragma unroll
        for (int c = 0; c < 4; c++) acc[r][c] = 0.0f;

    for (int k = 0; k < DD; k += 4) {
        float4 xv[4];
#pragma unroll
        for (int r = 0; r < 4; r++)
            xv[r] = *(const float4*)&xs[(rg + 8 * r) * DD + k];
#pragma unroll
        for (int kk = 0; kk < 4; kk++) {
            float4 w = *(const float4*)&ws[(k + kk) * DD + cq];
#pragma unroll
            for (int r = 0; r < 4; r++) {
                float xc = ((const float*)&xv[r])[kk];
                acc[r][0] += xc * w.x;
                acc[r][1] += xc * w.y;
                acc[r][2] += xc * w.z;
                acc[r][3] += xc * w.w;
            }
        }
    }

    float b0 = ld_in(Bp, cq, f32),     b1 = ld_in(Bp, cq + 1, f32);
    float b2 = ld_in(Bp, cq + 2, f32), b3 = ld_in(Bp, cq + 3, f32);
#pragma unroll
    for (int r = 0; r < 4; r++) {
        int row = row0 + rg + 8 * r;
        if (row < NN) {
            float o0 = 1.0f / (1.0f + __expf(-(acc[r][0] + b0)));
            float o1 = 1.0f / (1.0f + __expf(-(acc[r][1] + b1)));
            float o2 = 1.0f / (1.0f + __expf(-(acc[r][2] + b2)));
            float o3 = 1.0f / (1.0f + __expf(-(acc[r][3] + b3)));
            if (f32) {
                float4 o = {o0, o1, o2, o3};
                *(float4*)&((float*)Hp)[row * DD + cq] = o;
            } else {
                bf16* o = &((bf16*)Hp)[row * DD + cq];
                o[0] = __float2bfloat16(o0); o[1] = __float2bfloat16(o1);
                o[2] = __float2bfloat16(o2); o[3] = __float2bfloat16(o3);
            }
        }
    }
}

extern "C" void kernel_launch(void* const* d_in, const int* in_sizes, int n_in,
                              void* d_out, int out_size, void* d_ws, size_t ws_size,
                              hipStream_t stream) {
    const void* X  = d_in[0];
    const void* We = d_in[1];
    const void* be = d_in[2];
    const void* Wu = d_in[3];
    const void* bu = d_in[4];
    const int* adj = (const int*)d_in[5];

    // ws layout (persistent): FLAGS(256B) | ROWS((NN+1)*4 -> 200448B) | NBR(u16, 2*NE*2 = 2.4MB) | XBUF
    // DEG and CUR alias the XBUF region (dead before first gather).
    char* p = (char*)d_ws;
    int* FLAGS = (int*)p;                     p += 256;
    int* ROWS  = (int*)p;                     p += 200448;
    unsigned short* NBR = (unsigned short*)p; p += (size_t)2 * NE * 2;
    void* XB = (void*)p;                       // offset 2600704 (16B aligned)
    int* DEG = (int*)XB;
    int* CUR = DEG + NN;

    // fp32 XBUF if workspace allows, else bf16 XBUF (still well within tolerance)
    const size_t needA = 2600704 + (size_t)NN * DD * 4;
    const int xb32 = (ws_size >= needA + 1024) ? 1 : 0;

    k_sniff<<<1, 256, 0, stream>>>((const unsigned*)We, (const unsigned*)adj, FLAGS);
    hipMemsetAsync(DEG, 0, NN * sizeof(int), stream);
    k_degree<<<(NE + 255) / 256, 256, 0, stream>>>(adj, FLAGS, DEG);
    k_scan<<<1, 1024, 0, stream>>>(DEG, ROWS, CUR);
    k_fill<<<(NE + 255) / 256, 256, 0, stream>>>(adj, FLAGS, CUR, NBR);

    k_gemm_emb<<<(NN + GR - 1) / GR, 256, 0, stream>>>(X, We, be, d_out, FLAGS);

    for (int it = 0; it < ITERS; ++it) {
        k_gather<<<(NN * 64 + 255) / 256, 256, 0, stream>>>(d_out, ROWS, NBR, XB, FLAGS, xb32);
        k_gemm_upd<<<(NN + GR - 1) / GR, 256, 0, stream>>>(d_out, XB, Wu, bu, FLAGS, xb32);
    }
}

// Round 5
// 785.353 us; speedup vs baseline: 8.2379x; 1.1064x over previous
//
#include <hip/hip_runtime.h>
#include <hip/hip_bf16.h>

#define NN 50000
#define NE 600000
#define DD 128
#define ITERS 3
#define RB 64    // rows per MFMA block (4 waves x 16 rows)

typedef __bf16 bfrag __attribute__((ext_vector_type(8)));
typedef float  ffrag __attribute__((ext_vector_type(4)));

__device__ __forceinline__ float bfbits2f(unsigned v) { return __uint_as_float(v << 16); }
__device__ __forceinline__ unsigned f2bfbits(float f) {
    unsigned u = __float_as_uint(f);
    return (u + 0x7FFFu + ((u >> 16) & 1u)) >> 16;   // RNE
}

// ---------------- runtime dtype sniffer ----------------
// flags[0] = 1 if float inputs are fp32, 0 if bf16-packed
// flags[1] = 1 if adjacency is int64, 0 if int32
__global__ void k_sniff(const unsigned* __restrict__ w,
                        const unsigned* __restrict__ adj,
                        int* __restrict__ flags) {
    __shared__ int cnt[2];
    int tid = threadIdx.x;
    if (tid < 2) cnt[tid] = 0;
    __syncthreads();
    int c0 = 0, c1 = 0;
    for (int i = tid; i < 512; i += 256) {
        unsigned e = (w[i] >> 7) & 0xFFu;
        c0 += (e >= 0x60u && e <= 0x85u) ? 1 : 0;
    }
    for (int i = tid; i < 512; i += 256) {
        c1 += (adj[2 * i + 1] == 0u) ? 1 : 0;
    }
    atomicAdd(&cnt[0], c0);
    atomicAdd(&cnt[1], c1);
    __syncthreads();
    if (tid == 0) {
        flags[0] = (cnt[0] >= 256) ? 0 : 1;
        flags[1] = (cnt[1] >= 256) ? 1 : 0;
    }
}

__device__ __forceinline__ float ld_in(const void* p, int idx, int f32) {
    return f32 ? ((const float*)p)[idx]
               : bfbits2f(((const unsigned short*)p)[idx]);
}

__device__ __forceinline__ void ld_edge(const int* adj, int e, int i64, int& s, int& d) {
    if (i64) { s = adj[4 * e]; d = adj[4 * e + 2]; }
    else     { s = adj[2 * e]; d = adj[2 * e + 1]; }
}

// ---------------- CSR build ----------------
__global__ void k_degree(const int* __restrict__ adj, const int* __restrict__ flags,
                         int* __restrict__ deg) {
    int e = blockIdx.x * blockDim.x + threadIdx.x;
    if (e < NE) {
        int s, d;
        ld_edge(adj, e, flags[1], s, d);
        if ((unsigned)s < NN && (unsigned)d < NN) {
            atomicAdd(&deg[s], 1);
            atomicAdd(&deg[d], 1);
        }
    }
}

__global__ void k_scan(const int* __restrict__ deg, int* __restrict__ rows,
                       int* __restrict__ cur) {
    __shared__ int sh[1024];
    __shared__ int carry_s;
    const int tid = threadIdx.x;
    if (tid == 0) { carry_s = 0; rows[0] = 0; }
    __syncthreads();
    for (int base = 0; base < NN; base += 1024) {
        int i = base + tid;
        int v = (i < NN) ? deg[i] : 0;
        sh[tid] = v;
        __syncthreads();
        for (int off = 1; off < 1024; off <<= 1) {
            int t = (tid >= off) ? sh[tid - off] : 0;
            __syncthreads();
            sh[tid] += t;
            __syncthreads();
        }
        int incl = sh[tid];
        int c = carry_s;
        __syncthreads();
        if (i < NN) { rows[i + 1] = c + incl; cur[i] = c + incl - v; }
        if (tid == 1023) carry_s = c + sh[1023];
        __syncthreads();
    }
}

__global__ void k_fill(const int* __restrict__ adj, const int* __restrict__ flags,
                       int* __restrict__ cur, unsigned short* __restrict__ nbr) {
    int e = blockIdx.x * blockDim.x + threadIdx.x;
    if (e < NE) {
        int s, d;
        ld_edge(adj, e, flags[1], s, d);
        if ((unsigned)s < NN && (unsigned)d < NN) {
            int p = atomicAdd(&cur[s], 1);
            nbr[p] = (unsigned short)d;
            int q = atomicAdd(&cur[d], 1);
            nbr[q] = (unsigned short)s;
        }
    }
}

// ---------------- weight transpose: WT[n*128+k] = bf16(W[k*128+n]) ----------------
__global__ void k_prep(const void* __restrict__ We, const void* __restrict__ Wu,
                       const int* __restrict__ flags,
                       unsigned short* __restrict__ WeT, unsigned short* __restrict__ WuT) {
    const int f32 = flags[0];
    const int k = blockIdx.x;          // 128 blocks
    const int t = threadIdx.x;         // 256 threads
    if (t < DD) {
        WeT[t * DD + k] = (unsigned short)f2bfbits(ld_in(We, k * DD + t, f32));
    } else {
        int n = t - DD;
        WuT[n * DD + k] = (unsigned short)f2bfbits(ld_in(Wu, k * DD + n, f32));
    }
}

// ---------------- MFMA core shared by both GEMMs ----------------
// sA: RB x 128 bf16 (row-major), sWT: 128 x 128 bf16 (n-major). Wave computes its 16 rows.
__device__ __forceinline__ void mfma_core(const unsigned short* sA, const unsigned short* sWT,
                                          int wave, int lane, ffrag acc[8]) {
    const int m = lane & 15;
    const int quad = lane >> 4;
#pragma unroll
    for (int ks = 0; ks < 4; ks++) {
        const int k0 = ks * 32 + quad * 8;
        bfrag af = *(const bfrag*)&sA[(wave * 16 + m) * DD + k0];
#pragma unroll
        for (int ct = 0; ct < 8; ct++) {
            bfrag bf_ = *(const bfrag*)&sWT[(ct * 16 + m) * DD + k0];
            acc[ct] = __builtin_amdgcn_mfma_f32_16x16x32_bf16(af, bf_, acc[ct], 0, 0, 0);
        }
    }
}

// ---------------- GEMM 1: h0 = relu(X @ W_emb + b) -> bf16 Hout ----------------
__launch_bounds__(256, 3)
__global__ void k_emb(const void* __restrict__ Xp, const unsigned short* __restrict__ WTg,
                      const void* __restrict__ Bp, unsigned short* __restrict__ Hout,
                      const int* __restrict__ flags) {
    __shared__ __align__(16) unsigned short sWT[DD * DD];  // 32 KB
    __shared__ __align__(16) unsigned short sA[RB * DD];   // 16 KB
    const int tid  = threadIdx.x;
    const int wave = tid >> 6;
    const int lane = tid & 63;
    const int f32  = flags[0];
    const int rowbase = blockIdx.x * RB + wave * 16;

    for (int i = tid; i < 2048; i += 256)
        ((uint4*)sWT)[i] = ((const uint4*)WTg)[i];

    // stage A: lane covers 2 channels (cols 2*lane, 2*lane+1)
#pragma unroll 4
    for (int r = 0; r < 16; r++) {
        int row = rowbase + r;
        unsigned packed = 0;
        if (row < NN) {
            if (f32) {
                float2 v = ((const float2*)Xp)[row * 64 + lane];
                packed = f2bfbits(v.x) | (f2bfbits(v.y) << 16);
            } else {
                packed = ((const unsigned*)Xp)[row * 64 + lane];
            }
        }
        ((unsigned*)sA)[(wave * 16 + r) * 64 + lane] = packed;
    }
    __syncthreads();

    ffrag acc[8];
#pragma unroll
    for (int i = 0; i < 8; i++) acc[i] = (ffrag)(0.0f);
    mfma_core(sA, sWT, wave, lane, acc);

    const int m = lane & 15;
    const int quad = lane >> 4;
#pragma unroll
    for (int ct = 0; ct < 8; ct++) {
        int col = ct * 16 + m;
        float bb = ld_in(Bp, col, f32);
#pragma unroll
        for (int reg = 0; reg < 4; reg++) {
            int row = rowbase + quad * 4 + reg;
            if (row < NN) {
                float z = fmaxf(acc[ct][reg] + bb, 0.0f);
                Hout[row * DD + col] = (unsigned short)f2bfbits(z);
            }
        }
    }
}

// ---------------- fused: h_new = sigmoid(((h+agg)/(deg+1)) @ W_upd + b) ----------------
__launch_bounds__(256, 3)
__global__ void k_upd(const unsigned short* __restrict__ Hin,
                      unsigned short* __restrict__ HoutBf,
                      float* __restrict__ HoutF,
                      const int* __restrict__ rows, const unsigned short* __restrict__ nbr,
                      const unsigned short* __restrict__ WTg, const void* __restrict__ Bp,
                      const int* __restrict__ flags, int last) {
    __shared__ __align__(16) unsigned short sWT[DD * DD];  // 32 KB
    __shared__ __align__(16) unsigned short sA[RB * DD];   // 16 KB
    const int tid  = threadIdx.x;
    const int wave = tid >> 6;
    const int lane = tid & 63;
    const int f32  = flags[0];
    const int rowbase = blockIdx.x * RB + wave * 16;
    const unsigned* Hin32 = (const unsigned*)Hin;

    for (int i = tid; i < 2048; i += 256)
        ((uint4*)sWT)[i] = ((const uint4*)WTg)[i];

    // gather phase: 16 rows per wave; lane covers cols {2*lane, 2*lane+1}
    for (int r = 0; r < 16; r++) {
        int row = rowbase + r;
        unsigned packed = 0;
        if (row < NN) {
            unsigned self = Hin32[row * 64 + lane];
            float ax = bfbits2f(self & 0xFFFFu);
            float ay = bfbits2f(self >> 16);
            const int st = rows[row], en = rows[row + 1];
            int j = st;
            for (; j + 8 <= en; j += 8) {
                unsigned v0 = Hin32[(int)nbr[j    ] * 64 + lane];
                unsigned v1 = Hin32[(int)nbr[j + 1] * 64 + lane];
                unsigned v2 = Hin32[(int)nbr[j + 2] * 64 + lane];
                unsigned v3 = Hin32[(int)nbr[j + 3] * 64 + lane];
                unsigned v4 = Hin32[(int)nbr[j + 4] * 64 + lane];
                unsigned v5 = Hin32[(int)nbr[j + 5] * 64 + lane];
                unsigned v6 = Hin32[(int)nbr[j + 6] * 64 + lane];
                unsigned v7 = Hin32[(int)nbr[j + 7] * 64 + lane];
                ax += ((bfbits2f(v0 & 0xFFFFu) + bfbits2f(v1 & 0xFFFFu)) +
                       (bfbits2f(v2 & 0xFFFFu) + bfbits2f(v3 & 0xFFFFu))) +
                      ((bfbits2f(v4 & 0xFFFFu) + bfbits2f(v5 & 0xFFFFu)) +
                       (bfbits2f(v6 & 0xFFFFu) + bfbits2f(v7 & 0xFFFFu)));
                ay += ((bfbits2f(v0 >> 16) + bfbits2f(v1 >> 16)) +
                       (bfbits2f(v2 >> 16) + bfbits2f(v3 >> 16))) +
                      ((bfbits2f(v4 >> 16) + bfbits2f(v5 >> 16)) +
                       (bfbits2f(v6 >> 16) + bfbits2f(v7 >> 16)));
            }
            for (; j < en; ++j) {
                unsigned v = Hin32[(int)nbr[j] * 64 + lane];
                ax += bfbits2f(v & 0xFFFFu);
                ay += bfbits2f(v >> 16);
            }
            float inv = 1.0f / (float)(en - st + 1);
            packed = f2bfbits(ax * inv) | (f2bfbits(ay * inv) << 16);
        }
        ((unsigned*)sA)[(wave * 16 + r) * 64 + lane] = packed;
    }
    __syncthreads();

    ffrag acc[8];
#pragma unroll
    for (int i = 0; i < 8; i++) acc[i] = (ffrag)(0.0f);
    mfma_core(sA, sWT, wave, lane, acc);

    const int m = lane & 15;
    const int quad = lane >> 4;
#pragma unroll
    for (int ct = 0; ct < 8; ct++) {
        int col = ct * 16 + m;
        float bb = ld_in(Bp, col, f32);
#pragma unroll
        for (int reg = 0; reg < 4; reg++) {
            int row = rowbase + quad * 4 + reg;
            if (row < NN) {
                float s = 1.0f / (1.0f + __expf(-(acc[ct][reg] + bb)));
                if (!last) {
                    HoutBf[row * DD + col] = (unsigned short)f2bfbits(s);
                } else if (f32) {
                    HoutF[row * DD + col] = s;
                } else {
                    ((unsigned short*)HoutF)[row * DD + col] = (unsigned short)f2bfbits(s);
                }
            }
        }
    }
}

extern "C" void kernel_launch(void* const* d_in, const int* in_sizes, int n_in,
                              void* d_out, int out_size, void* d_ws, size_t ws_size,
                              hipStream_t stream) {
    const void* X  = d_in[0];
    const void* We = d_in[1];
    const void* be = d_in[2];
    const void* Wu = d_in[3];
    const void* bu = d_in[4];
    const int* adj = (const int*)d_in[5];

    // ws: FLAGS(256B) | ROWS((NN+1)*4) | NBR(1.2M u16 = 2.4MB) | WeT(32KB) | WuT(32KB) | HA(bf16 12.8MB)
    // DEG/CUR alias HA (dead before k_emb). HB aliases d_out's first 12.8 MB.
    char* p = (char*)d_ws;
    int* FLAGS = (int*)p;                       p += 256;
    int* ROWS  = (int*)p;                       p += ((NN + 1) * 4 + 252) / 256 * 256;
    unsigned short* NBR = (unsigned short*)p;   p += (size_t)2 * NE * 2;
    unsigned short* WeT = (unsigned short*)p;   p += DD * DD * 2;
    unsigned short* WuT = (unsigned short*)p;   p += DD * DD * 2;
    unsigned short* HA  = (unsigned short*)p;
    int* DEG = (int*)HA;
    int* CUR = DEG + NN;
    unsigned short* HB = (unsigned short*)d_out;

    const int GB = (NN + RB - 1) / RB;   // 782 MFMA blocks

    k_sniff<<<1, 256, 0, stream>>>((const unsigned*)We, (const unsigned*)adj, FLAGS);
    hipMemsetAsync(DEG, 0, NN * sizeof(int), stream);
    k_degree<<<(NE + 255) / 256, 256, 0, stream>>>(adj, FLAGS, DEG);
    k_scan<<<1, 1024, 0, stream>>>(DEG, ROWS, CUR);
    k_fill<<<(NE + 255) / 256, 256, 0, stream>>>(adj, FLAGS, CUR, NBR);
    k_prep<<<DD, 256, 0, stream>>>(We, Wu, FLAGS, WeT, WuT);

    k_emb<<<GB, 256, 0, stream>>>(X, WeT, be, HA, FLAGS);

    // iter 1: HA -> HB (in d_out), iter 2: HB -> HA, iter 3: HA -> d_out (final dtype)
    k_upd<<<GB, 256, 0, stream>>>(HA, HB, (float*)d_out, ROWS, NBR, WuT, bu, FLAGS, 0);
    k_upd<<<GB, 256, 0, stream>>>(HB, HA, (float*)d_out, ROWS, NBR, WuT, bu, FLAGS, 0);
    k_upd<<<GB, 256, 0, stream>>>(HA, HA, (float*)d_out, ROWS, NBR, WuT, bu, FLAGS, 1);
}

// Round 6
// 474.150 us; speedup vs baseline: 13.6447x; 1.6563x over previous
//
#include <hip/hip_runtime.h>
#include <hip/hip_bf16.h>

#define NN 50000
#define NE 600000
#define DD 128
#define RB 64    // rows per MFMA block (4 waves x 16 rows)

typedef __bf16 bfrag __attribute__((ext_vector_type(8)));
typedef float  ffrag __attribute__((ext_vector_type(4)));

__device__ __forceinline__ float bfbits2f(unsigned v) { return __uint_as_float(v << 16); }
__device__ __forceinline__ unsigned f2bfbits(float f) {
    unsigned u = __float_as_uint(f);
    return (u + 0x7FFFu + ((u >> 16) & 1u)) >> 16;   // RNE
}

// ---------------- runtime dtype sniffer ----------------
__global__ void k_sniff(const unsigned* __restrict__ w,
                        const unsigned* __restrict__ adj,
                        int* __restrict__ flags) {
    __shared__ int cnt[2];
    int tid = threadIdx.x;
    if (tid < 2) cnt[tid] = 0;
    __syncthreads();
    int c0 = 0, c1 = 0;
    for (int i = tid; i < 512; i += 256) {
        unsigned e = (w[i] >> 7) & 0xFFu;
        c0 += (e >= 0x60u && e <= 0x85u) ? 1 : 0;
    }
    for (int i = tid; i < 512; i += 256) {
        c1 += (adj[2 * i + 1] == 0u) ? 1 : 0;
    }
    atomicAdd(&cnt[0], c0);
    atomicAdd(&cnt[1], c1);
    __syncthreads();
    if (tid == 0) {
        flags[0] = (cnt[0] >= 256) ? 0 : 1;   // fp32 inputs?
        flags[1] = (cnt[1] >= 256) ? 1 : 0;   // int64 adjacency?
    }
}

__device__ __forceinline__ float ld_in(const void* p, int idx, int f32) {
    return f32 ? ((const float*)p)[idx]
               : bfbits2f(((const unsigned short*)p)[idx]);
}

__device__ __forceinline__ void ld_edge(const int* adj, int e, int i64, int& s, int& d) {
    if (i64) { s = adj[4 * e]; d = adj[4 * e + 2]; }
    else     { s = adj[2 * e]; d = adj[2 * e + 1]; }
}

// ---------------- CSR build ----------------
__global__ void k_degree(const int* __restrict__ adj, const int* __restrict__ flags,
                         int* __restrict__ deg) {
    int e = blockIdx.x * blockDim.x + threadIdx.x;
    if (e < NE) {
        int s, d;
        ld_edge(adj, e, flags[1], s, d);
        if ((unsigned)s < NN && (unsigned)d < NN) {
            atomicAdd(&deg[s], 1);
            atomicAdd(&deg[d], 1);
        }
    }
}

// hierarchical scan: 49 blocks x 1024, then serial over 49 sums, then offset-add
__global__ void k_scan1(const int* __restrict__ deg, int* __restrict__ rows,
                        int* __restrict__ sums) {
    __shared__ int sh[1024];
    const int tid = threadIdx.x;
    const int i = blockIdx.x * 1024 + tid;
    sh[tid] = (i < NN) ? deg[i] : 0;
    __syncthreads();
    for (int off = 1; off < 1024; off <<= 1) {
        int t = (tid >= off) ? sh[tid - off] : 0;
        __syncthreads();
        sh[tid] += t;
        __syncthreads();
    }
    if (i < NN) rows[i + 1] = sh[tid];
    if (tid == 1023) sums[blockIdx.x] = sh[1023];
}

__global__ void k_scan2(int* __restrict__ sums, int nb) {
    if (threadIdx.x == 0) {
        int run = 0;
        for (int b = 0; b < nb; b++) { int t = sums[b]; sums[b] = run; run += t; }
    }
}

__global__ void k_scan3(const int* __restrict__ deg, const int* __restrict__ sums,
                        int* __restrict__ rows, int* __restrict__ cur) {
    int i = blockIdx.x * 1024 + threadIdx.x;
    if (i < NN) {
        int r = rows[i + 1] + sums[blockIdx.x];
        rows[i + 1] = r;
        cur[i] = r - deg[i];
        if (i == 0) rows[0] = 0;
    }
}

__global__ void k_fill(const int* __restrict__ adj, const int* __restrict__ flags,
                       int* __restrict__ cur, unsigned short* __restrict__ nbr) {
    int e = blockIdx.x * blockDim.x + threadIdx.x;
    if (e < NE) {
        int s, d;
        ld_edge(adj, e, flags[1], s, d);
        if ((unsigned)s < NN && (unsigned)d < NN) {
            int p = atomicAdd(&cur[s], 1);
            nbr[p] = (unsigned short)d;
            int q = atomicAdd(&cur[d], 1);
            nbr[q] = (unsigned short)s;
        }
    }
}

// ---------------- weight transpose: WT[n*128+k] = bf16(W[k*128+n]) ----------------
__global__ void k_prep(const void* __restrict__ We, const void* __restrict__ Wu,
                       const int* __restrict__ flags,
                       unsigned short* __restrict__ WeT, unsigned short* __restrict__ WuT) {
    const int f32 = flags[0];
    const int k = blockIdx.x;
    const int t = threadIdx.x;
    if (t < DD) {
        WeT[t * DD + k] = (unsigned short)f2bfbits(ld_in(We, k * DD + t, f32));
    } else {
        int n = t - DD;
        WuT[n * DD + k] = (unsigned short)f2bfbits(ld_in(Wu, k * DD + n, f32));
    }
}

// ---------------- MFMA core ----------------
// sA: RB x 128 bf16 row-major, sWT: 128 x 128 bf16 n-major. Wave computes its 16 rows.
__device__ __forceinline__ void mfma_core(const unsigned short* sA, const unsigned short* sWT,
                                          int wave, int lane, ffrag acc[8]) {
    const int m = lane & 15;
    const int quad = lane >> 4;
#pragma unroll
    for (int ks = 0; ks < 4; ks++) {
        const int k0 = ks * 32 + quad * 8;
        bfrag af = *(const bfrag*)&sA[(wave * 16 + m) * DD + k0];
#pragma unroll
        for (int ct = 0; ct < 8; ct++) {
            bfrag bf_ = *(const bfrag*)&sWT[(ct * 16 + m) * DD + k0];
            acc[ct] = __builtin_amdgcn_mfma_f32_16x16x32_bf16(af, bf_, acc[ct], 0, 0, 0);
        }
    }
}

// ---------------- GEMM 1: h0 = relu(X @ W_emb + b) -> bf16 HA ----------------
__launch_bounds__(256, 3)
__global__ void k_emb(const void* __restrict__ Xp, const unsigned short* __restrict__ WTg,
                      const void* __restrict__ Bp, unsigned short* __restrict__ Hout,
                      const int* __restrict__ flags) {
    __shared__ __align__(16) unsigned short sWT[DD * DD];  // 32 KB
    __shared__ __align__(16) unsigned short sA[RB * DD];   // 16 KB
    const int tid  = threadIdx.x;
    const int wave = tid >> 6;
    const int lane = tid & 63;
    const int f32  = flags[0];
    const int rowbase = blockIdx.x * RB + wave * 16;

    for (int i = tid; i < 2048; i += 256)
        ((uint4*)sWT)[i] = ((const uint4*)WTg)[i];

#pragma unroll 4
    for (int r = 0; r < 16; r++) {
        int row = rowbase + r;
        unsigned packed = 0;
        if (row < NN) {
            if (f32) {
                float2 v = ((const float2*)Xp)[row * 64 + lane];
                packed = f2bfbits(v.x) | (f2bfbits(v.y) << 16);
            } else {
                packed = ((const unsigned*)Xp)[row * 64 + lane];
            }
        }
        ((unsigned*)sA)[(wave * 16 + r) * 64 + lane] = packed;
    }
    __syncthreads();

    ffrag acc[8];
#pragma unroll
    for (int i = 0; i < 8; i++) acc[i] = (ffrag)(0.0f);
    mfma_core(sA, sWT, wave, lane, acc);

    const int m = lane & 15;
    const int quad = lane >> 4;
#pragma unroll
    for (int ct = 0; ct < 8; ct++) {
        int col = ct * 16 + m;
        float bb = ld_in(Bp, col, f32);
#pragma unroll
        for (int reg = 0; reg < 4; reg++) {
            int row = rowbase + quad * 4 + reg;
            if (row < NN) {
                float z = fmaxf(acc[ct][reg] + bb, 0.0f);
                Hout[row * DD + col] = (unsigned short)f2bfbits(z);
            }
        }
    }
}

// ---------------- gather: XB[row] = bf16((h[row] + sum_nbr h) / (deg+1)) ----------------
// no LDS, low VGPR -> high occupancy for memory-level parallelism
__launch_bounds__(256)
__global__ void k_gather(const unsigned* __restrict__ Hin32, const int* __restrict__ rows,
                         const unsigned short* __restrict__ nbr,
                         unsigned* __restrict__ XBo) {
    const int gid  = blockIdx.x * 256 + threadIdx.x;
    const int row  = gid >> 6;              // one wave per node
    const int lane = threadIdx.x & 63;      // 2 channels per lane
    if (row >= NN) return;
    unsigned self = Hin32[row * 64 + lane];
    float ax = bfbits2f(self & 0xFFFFu);
    float ay = bfbits2f(self >> 16);
    const int st = rows[row], en = rows[row + 1];
    int j = st;
    for (; j + 8 <= en; j += 8) {
        unsigned v0 = Hin32[(int)nbr[j    ] * 64 + lane];
        unsigned v1 = Hin32[(int)nbr[j + 1] * 64 + lane];
        unsigned v2 = Hin32[(int)nbr[j + 2] * 64 + lane];
        unsigned v3 = Hin32[(int)nbr[j + 3] * 64 + lane];
        unsigned v4 = Hin32[(int)nbr[j + 4] * 64 + lane];
        unsigned v5 = Hin32[(int)nbr[j + 5] * 64 + lane];
        unsigned v6 = Hin32[(int)nbr[j + 6] * 64 + lane];
        unsigned v7 = Hin32[(int)nbr[j + 7] * 64 + lane];
        ax += ((bfbits2f(v0 & 0xFFFFu) + bfbits2f(v1 & 0xFFFFu)) +
               (bfbits2f(v2 & 0xFFFFu) + bfbits2f(v3 & 0xFFFFu))) +
              ((bfbits2f(v4 & 0xFFFFu) + bfbits2f(v5 & 0xFFFFu)) +
               (bfbits2f(v6 & 0xFFFFu) + bfbits2f(v7 & 0xFFFFu)));
        ay += ((bfbits2f(v0 >> 16) + bfbits2f(v1 >> 16)) +
               (bfbits2f(v2 >> 16) + bfbits2f(v3 >> 16))) +
              ((bfbits2f(v4 >> 16) + bfbits2f(v5 >> 16)) +
               (bfbits2f(v6 >> 16) + bfbits2f(v7 >> 16)));
    }
    for (; j < en; ++j) {
        unsigned v = Hin32[(int)nbr[j] * 64 + lane];
        ax += bfbits2f(v & 0xFFFFu);
        ay += bfbits2f(v >> 16);
    }
    float inv = 1.0f / (float)(en - st + 1);
    XBo[row * 64 + lane] = f2bfbits(ax * inv) | (f2bfbits(ay * inv) << 16);
}

// ---------------- GEMM 2: h_new = sigmoid(XB @ W_upd + b) ----------------
__launch_bounds__(256, 3)
__global__ void k_gemmB(const unsigned short* __restrict__ XB,
                        const unsigned short* __restrict__ WTg, const void* __restrict__ Bp,
                        unsigned short* __restrict__ HoutBf, float* __restrict__ HoutF,
                        const int* __restrict__ flags, int last) {
    __shared__ __align__(16) unsigned short sWT[DD * DD];  // 32 KB
    __shared__ __align__(16) unsigned short sA[RB * DD];   // 16 KB
    const int tid  = threadIdx.x;
    const int wave = tid >> 6;
    const int lane = tid & 63;
    const int f32  = flags[0];
    const int rowbase = blockIdx.x * RB + wave * 16;

    for (int i = tid; i < 2048; i += 256)
        ((uint4*)sWT)[i] = ((const uint4*)WTg)[i];

    // stage A tile: contiguous 16 KB copy (XB padded, over-read safe; pad rows unused)
    const uint4* src = (const uint4*)(XB + (size_t)blockIdx.x * RB * DD);
#pragma unroll
    for (int i = tid; i < 1024; i += 256)
        ((uint4*)sA)[i] = src[i];
    __syncthreads();

    ffrag acc[8];
#pragma unroll
    for (int i = 0; i < 8; i++) acc[i] = (ffrag)(0.0f);
    mfma_core(sA, sWT, wave, lane, acc);

    const int m = lane & 15;
    const int quad = lane >> 4;
#pragma unroll
    for (int ct = 0; ct < 8; ct++) {
        int col = ct * 16 + m;
        float bb = ld_in(Bp, col, f32);
#pragma unroll
        for (int reg = 0; reg < 4; reg++) {
            int row = rowbase + quad * 4 + reg;
            if (row < NN) {
                float s = 1.0f / (1.0f + __expf(-(acc[ct][reg] + bb)));
                if (!last) {
                    HoutBf[row * DD + col] = (unsigned short)f2bfbits(s);
                } else if (f32) {
                    HoutF[row * DD + col] = s;
                } else {
                    ((unsigned short*)HoutF)[row * DD + col] = (unsigned short)f2bfbits(s);
                }
            }
        }
    }
}

extern "C" void kernel_launch(void* const* d_in, const int* in_sizes, int n_in,
                              void* d_out, int out_size, void* d_ws, size_t ws_size,
                              hipStream_t stream) {
    const void* X  = d_in[0];
    const void* We = d_in[1];
    const void* be = d_in[2];
    const void* Wu = d_in[3];
    const void* bu = d_in[4];
    const int* adj = (const int*)d_in[5];

    // ws: FLAGS | ROWS | SUMS | NBR | WeT | WuT | XB(+slack). DEG/CUR alias XB (dead pre-emb).
    // Total ~15.5 MB (same footprint as rounds 4/5, proven).
    char* p = (char*)d_ws;
    int* FLAGS = (int*)p;                       p += 256;
    int* ROWS  = (int*)p;                       p += ((NN + 1) * 4 + 252) / 256 * 256;
    int* SUMS  = (int*)p;                       p += 256;
    unsigned short* NBR = (unsigned short*)p;   p += (size_t)2 * NE * 2;
    unsigned short* WeT = (unsigned short*)p;   p += DD * DD * 2;
    unsigned short* WuT = (unsigned short*)p;   p += DD * DD * 2;
    unsigned short* XB  = (unsigned short*)p;   // 12.8 MB + 16 KB over-read slack
    int* DEG = (int*)XB;
    int* CUR = DEG + NN;

    // h ping-pongs inside d_out: HA = upper half (bytes 12.8M..25.6M)
    unsigned short* HA = (unsigned short*)d_out + (size_t)NN * DD / 2 * 2; // NN*DD u16 offset? no:
    HA = (unsigned short*)d_out + (size_t)NN * DD;   // element offset NN*DD u16 = 12.8 MB

    const int GB = (NN + RB - 1) / RB;           // 782 MFMA blocks
    const int SB = (NN + 1023) / 1024;           // 49 scan blocks

    k_sniff<<<1, 256, 0, stream>>>((const unsigned*)We, (const unsigned*)adj, FLAGS);
    hipMemsetAsync(DEG, 0, NN * sizeof(int), stream);
    k_degree<<<(NE + 255) / 256, 256, 0, stream>>>(adj, FLAGS, DEG);
    k_scan1<<<SB, 1024, 0, stream>>>(DEG, ROWS, SUMS);
    k_scan2<<<1, 64, 0, stream>>>(SUMS, SB);
    k_scan3<<<SB, 1024, 0, stream>>>(DEG, SUMS, ROWS, CUR);
    k_fill<<<(NE + 255) / 256, 256, 0, stream>>>(adj, FLAGS, CUR, NBR);
    k_prep<<<DD, 256, 0, stream>>>(We, Wu, FLAGS, WeT, WuT);

    k_emb<<<GB, 256, 0, stream>>>(X, WeT, be, HA, FLAGS);

    const int GGB = (NN * 64 + 255) / 256;       // 12500 gather blocks
    for (int it = 0; it < 3; ++it) {
        int last = (it == 2);
        k_gather<<<GGB, 256, 0, stream>>>((const unsigned*)HA, ROWS, NBR, (unsigned*)XB);
        k_gemmB<<<GB, 256, 0, stream>>>(XB, WuT, bu, HA, (float*)d_out, FLAGS, last);
    }
}

// Round 7
// 454.675 us; speedup vs baseline: 14.2292x; 1.0428x over previous
//
#include <hip/hip_runtime.h>
#include <hip/hip_bf16.h>

#define NN 50000
#define NE 600000
#define DD 128
#define RB 64    // rows per MFMA block (4 waves x 16 rows)
#define NSHARD_DIV 6250   // NN/8 node-range per XCD shard

typedef __bf16 bfrag __attribute__((ext_vector_type(8)));
typedef float  ffrag __attribute__((ext_vector_type(4)));

__device__ __forceinline__ float bfbits2f(unsigned v) { return __uint_as_float(v << 16); }
__device__ __forceinline__ unsigned f2bfbits(float f) {
    unsigned u = __float_as_uint(f);
    return (u + 0x7FFFu + ((u >> 16) & 1u)) >> 16;   // RNE
}

__device__ __forceinline__ float ld_in(const void* p, int idx, int f32) {
    return f32 ? ((const float*)p)[idx]
               : bfbits2f(((const unsigned short*)p)[idx]);
}

__device__ __forceinline__ void ld_edge(const int* adj, int e, int i64, int& s, int& d) {
    if (i64) { s = adj[4 * e]; d = adj[4 * e + 2]; }
    else     { s = adj[2 * e]; d = adj[2 * e + 1]; }
}

// ---------------- sniffer + DEG zeroing (64 blocks) ----------------
__global__ void k_sniffzero(const unsigned* __restrict__ w, const unsigned* __restrict__ adj,
                            int* __restrict__ flags, int* __restrict__ deg) {
    for (int i = blockIdx.x * 256 + threadIdx.x; i < NN; i += 64 * 256) deg[i] = 0;
    if (blockIdx.x != 0) return;
    __shared__ int cnt[2];
    int tid = threadIdx.x;
    if (tid < 2) cnt[tid] = 0;
    __syncthreads();
    int c0 = 0, c1 = 0;
    for (int i = tid; i < 512; i += 256) {
        unsigned e = (w[i] >> 7) & 0xFFu;
        c0 += (e >= 0x60u && e <= 0x85u) ? 1 : 0;       // plausible low-half bf16?
        c1 += (adj[2 * i + 1] == 0u) ? 1 : 0;           // int64 zero high words?
    }
    atomicAdd(&cnt[0], c0);
    atomicAdd(&cnt[1], c1);
    __syncthreads();
    if (tid == 0) {
        flags[0] = (cnt[0] >= 256) ? 0 : 1;   // fp32 inputs?
        flags[1] = (cnt[1] >= 256) ? 1 : 0;   // int64 adjacency?
    }
}

// ---------------- degree + rank capture + edge compaction + weight prep ----------------
// blocks [0,128): transpose weights to bf16 WT[n][k]; blocks [128, ...): per-edge work
__global__ void k_degprep(const int* __restrict__ adj, const int* __restrict__ flags,
                          const void* __restrict__ We, const void* __restrict__ Wu,
                          unsigned short* __restrict__ WeT, unsigned short* __restrict__ WuT,
                          int* __restrict__ deg, unsigned* __restrict__ edg,
                          unsigned short* __restrict__ rnk) {
    const int f32 = flags[0];
    if (blockIdx.x < DD) {
        const int k = blockIdx.x, t = threadIdx.x;
        if (t < DD) {
            WeT[t * DD + k] = (unsigned short)f2bfbits(ld_in(We, k * DD + t, f32));
        } else {
            int n = t - DD;
            WuT[n * DD + k] = (unsigned short)f2bfbits(ld_in(Wu, k * DD + n, f32));
        }
        return;
    }
    int e = (blockIdx.x - DD) * 256 + threadIdx.x;
    if (e < NE) {
        int s, d;
        ld_edge(adj, e, flags[1], s, d);
        if ((unsigned)s < NN && (unsigned)d < NN) {
            int rs = atomicAdd(&deg[s], 1);   // rank of this edge within node s
            int rd = atomicAdd(&deg[d], 1);
            edg[e] = (unsigned)s | ((unsigned)d << 16);
            rnk[e] = (unsigned short)((rs & 0xFF) | ((rd & 0xFF) << 8));
        } else {
            edg[e] = 0xFFFFFFFFu;             // sentinel: skip in fill
        }
    }
}

// ---------------- hierarchical scan: 49x1024 partials, wave-scan of sums, offset-add ----
__global__ void k_scan1(const int* __restrict__ deg, int* __restrict__ rows,
                        int* __restrict__ sums) {
    __shared__ int sh[1024];
    const int tid = threadIdx.x;
    const int i = blockIdx.x * 1024 + tid;
    sh[tid] = (i < NN) ? deg[i] : 0;
    __syncthreads();
    for (int off = 1; off < 1024; off <<= 1) {
        int t = (tid >= off) ? sh[tid - off] : 0;
        __syncthreads();
        sh[tid] += t;
        __syncthreads();
    }
    if (i < NN) rows[i + 1] = sh[tid];
    if (tid == 1023) sums[blockIdx.x] = sh[1023];
}

__global__ void k_scan2(int* __restrict__ sums, int nb) {
    int t = threadIdx.x;                 // one wave of 64
    int v = (t < nb) ? sums[t] : 0;
    int x = v;
    for (int off = 1; off < 64; off <<= 1) {
        int y = __shfl_up(x, off, 64);
        if (t >= off) x += y;
    }
    if (t < nb) sums[t] = x - v;         // exclusive
}

__global__ void k_scan3(const int* __restrict__ sums, int* __restrict__ rows) {
    int i = blockIdx.x * 1024 + threadIdx.x;
    if (i < NN) {
        rows[i + 1] += sums[blockIdx.x];
        if (i == 0) rows[0] = 0;
    }
}

// ---------------- XCD-sharded, atomic-free CSR fill ----------------
// blockIdx&7 = shard (maps to XCD by round-robin dispatch); blockIdx>>3 = edge chunk
__launch_bounds__(256)
__global__ void k_fill(const unsigned* __restrict__ edg, const unsigned short* __restrict__ rnk,
                       const int* __restrict__ rows, unsigned short* __restrict__ nbr) {
    const int shard = blockIdx.x & 7;
    const int e = (blockIdx.x >> 3) * 256 + threadIdx.x;
    if (e >= NE) return;
    unsigned v = edg[e];
    if (v == 0xFFFFFFFFu) return;
    int s = v & 0xFFFFu, d = v >> 16;
    unsigned short rk = rnk[e];
    if (s / NSHARD_DIV == shard) nbr[rows[s] + (rk & 0xFF)] = (unsigned short)d;
    if (d / NSHARD_DIV == shard) nbr[rows[d] + (rk >> 8)]   = (unsigned short)s;
}

// ---------------- MFMA core ----------------
// sA: RB x 128 bf16 row-major, sWT: 128 x 128 bf16 n-major. Wave computes its 16 rows.
__device__ __forceinline__ void mfma_core(const unsigned short* sA, const unsigned short* sWT,
                                          int wave, int lane, ffrag acc[8]) {
    const int m = lane & 15;
    const int quad = lane >> 4;
#pragma unroll
    for (int ks = 0; ks < 4; ks++) {
        const int k0 = ks * 32 + quad * 8;
        bfrag af = *(const bfrag*)&sA[(wave * 16 + m) * DD + k0];
#pragma unroll
        for (int ct = 0; ct < 8; ct++) {
            bfrag bf_ = *(const bfrag*)&sWT[(ct * 16 + m) * DD + k0];
            acc[ct] = __builtin_amdgcn_mfma_f32_16x16x32_bf16(af, bf_, acc[ct], 0, 0, 0);
        }
    }
}

// ---------------- GEMM 1: h0 = relu(X @ W_emb + b) -> bf16 HA ----------------
__launch_bounds__(256, 3)
__global__ void k_emb(const void* __restrict__ Xp, const unsigned short* __restrict__ WTg,
                      const void* __restrict__ Bp, unsigned short* __restrict__ Hout,
                      const int* __restrict__ flags) {
    __shared__ __align__(16) unsigned short sWT[DD * DD];  // 32 KB
    __shared__ __align__(16) unsigned short sA[RB * DD];   // 16 KB
    const int tid  = threadIdx.x;
    const int wave = tid >> 6;
    const int lane = tid & 63;
    const int f32  = flags[0];
    const int rowbase = blockIdx.x * RB + wave * 16;

    for (int i = tid; i < 2048; i += 256)
        ((uint4*)sWT)[i] = ((const uint4*)WTg)[i];

#pragma unroll 4
    for (int r = 0; r < 16; r++) {
        int row = rowbase + r;
        unsigned packed = 0;
        if (row < NN) {
            if (f32) {
                float2 v = ((const float2*)Xp)[row * 64 + lane];
                packed = f2bfbits(v.x) | (f2bfbits(v.y) << 16);
            } else {
                packed = ((const unsigned*)Xp)[row * 64 + lane];
            }
        }
        ((unsigned*)sA)[(wave * 16 + r) * 64 + lane] = packed;
    }
    __syncthreads();

    ffrag acc[8];
#pragma unroll
    for (int i = 0; i < 8; i++) acc[i] = (ffrag)(0.0f);
    mfma_core(sA, sWT, wave, lane, acc);

    const int m = lane & 15;
    const int quad = lane >> 4;
#pragma unroll
    for (int ct = 0; ct < 8; ct++) {
        int col = ct * 16 + m;
        float bb = ld_in(Bp, col, f32);
#pragma unroll
        for (int reg = 0; reg < 4; reg++) {
            int row = rowbase + quad * 4 + reg;
            if (row < NN) {
                float z = fmaxf(acc[ct][reg] + bb, 0.0f);
                Hout[row * DD + col] = (unsigned short)f2bfbits(z);
            }
        }
    }
}

// ---------------- channel-sliced XCD-affine gather ----------------
// slice = blockIdx&3 -> 16 u32 (=64 B, one cache line) of each h row; each XCD's L2
// then only caches a 3.2 MB column-slice of h (fits in 4 MB). Wave = 4 rows x 16 lanes.
__launch_bounds__(256)
__global__ void k_gather(const unsigned* __restrict__ H32, const int* __restrict__ rows,
                         const unsigned short* __restrict__ nbr,
                         unsigned* __restrict__ XB32) {
    const int slice = blockIdx.x & 3;
    const int tile  = blockIdx.x >> 2;          // 16 rows per tile
    const int wave  = threadIdx.x >> 6;
    const int lane  = threadIdx.x & 63;
    const int rsub  = lane >> 4;                // 0..3
    const int c     = lane & 15;
    const int row   = tile * 16 + wave * 4 + rsub;
    const int col   = slice * 16 + c;           // u32 column (2 channels)
    int st = 0, en = 0;
    unsigned selfv = 0;
    if (row < NN) {
        st = rows[row]; en = rows[row + 1];
        selfv = H32[row * 64 + col];
    }
    float ax = bfbits2f(selfv & 0xFFFFu);
    float ay = bfbits2f(selfv >> 16);
    int j = st;
    for (; j + 4 <= en; j += 4) {
        int n0 = nbr[j], n1 = nbr[j + 1], n2 = nbr[j + 2], n3 = nbr[j + 3];
        unsigned v0 = H32[n0 * 64 + col];
        unsigned v1 = H32[n1 * 64 + col];
        unsigned v2 = H32[n2 * 64 + col];
        unsigned v3 = H32[n3 * 64 + col];
        ax += (bfbits2f(v0 & 0xFFFFu) + bfbits2f(v1 & 0xFFFFu)) +
              (bfbits2f(v2 & 0xFFFFu) + bfbits2f(v3 & 0xFFFFu));
        ay += (bfbits2f(v0 >> 16) + bfbits2f(v1 >> 16)) +
              (bfbits2f(v2 >> 16) + bfbits2f(v3 >> 16));
    }
    for (; j < en; ++j) {
        unsigned v = H32[(int)nbr[j] * 64 + col];
        ax += bfbits2f(v & 0xFFFFu);
        ay += bfbits2f(v >> 16);
    }
    if (row < NN) {
        float inv = 1.0f / (float)(en - st + 1);
        XB32[row * 64 + col] = f2bfbits(ax * inv) | (f2bfbits(ay * inv) << 16);
    }
}

// ---------------- GEMM 2: h_new = sigmoid(XB @ W_upd + b) ----------------
__launch_bounds__(256, 3)
__global__ void k_gemmB(const unsigned short* __restrict__ XB,
                        const unsigned short* __restrict__ WTg, const void* __restrict__ Bp,
                        unsigned short* __restrict__ HoutBf, float* __restrict__ HoutF,
                        const int* __restrict__ flags, int last) {
    __shared__ __align__(16) unsigned short sWT[DD * DD];  // 32 KB
    __shared__ __align__(16) unsigned short sA[RB * DD];   // 16 KB
    const int tid  = threadIdx.x;
    const int wave = tid >> 6;
    const int lane = tid & 63;
    const int f32  = flags[0];
    const int rowbase = blockIdx.x * RB + wave * 16;

    for (int i = tid; i < 2048; i += 256)
        ((uint4*)sWT)[i] = ((const uint4*)WTg)[i];

    const uint4* src = (const uint4*)(XB + (size_t)blockIdx.x * RB * DD);
#pragma unroll
    for (int i = tid; i < 1024; i += 256)
        ((uint4*)sA)[i] = src[i];
    __syncthreads();

    ffrag acc[8];
#pragma unroll
    for (int i = 0; i < 8; i++) acc[i] = (ffrag)(0.0f);
    mfma_core(sA, sWT, wave, lane, acc);

    const int m = lane & 15;
    const int quad = lane >> 4;
#pragma unroll
    for (int ct = 0; ct < 8; ct++) {
        int col = ct * 16 + m;
        float bb = ld_in(Bp, col, f32);
#pragma unroll
        for (int reg = 0; reg < 4; reg++) {
            int row = rowbase + quad * 4 + reg;
            if (row < NN) {
                float s = 1.0f / (1.0f + __expf(-(acc[ct][reg] + bb)));
                if (!last) {
                    HoutBf[row * DD + col] = (unsigned short)f2bfbits(s);
                } else if (f32) {
                    HoutF[row * DD + col] = s;
                } else {
                    ((unsigned short*)HoutF)[row * DD + col] = (unsigned short)f2bfbits(s);
                }
            }
        }
    }
}

extern "C" void kernel_launch(void* const* d_in, const int* in_sizes, int n_in,
                              void* d_out, int out_size, void* d_ws, size_t ws_size,
                              hipStream_t stream) {
    const void* X  = d_in[0];
    const void* We = d_in[1];
    const void* be = d_in[2];
    const void* Wu = d_in[3];
    const void* bu = d_in[4];
    const int* adj = (const int*)d_in[5];

    // ws: FLAGS | ROWS | SUMS | NBR(2.4M) | WeT | WuT | EDG(2.4M) | RNK(1.2M) | XB(12.8M+slack)
    // DEG aliases XB (dead after scan1, before first gather). Total ~19.1 MB (<26 MB proven).
    char* p = (char*)d_ws;
    int* FLAGS = (int*)p;                       p += 256;
    int* ROWS  = (int*)p;                       p += ((NN + 1) * 4 + 252) / 256 * 256;
    int* SUMS  = (int*)p;                       p += 256;
    unsigned short* NBR = (unsigned short*)p;   p += (size_t)2 * NE * 2;
    unsigned short* WeT = (unsigned short*)p;   p += DD * DD * 2;
    unsigned short* WuT = (unsigned short*)p;   p += DD * DD * 2;
    unsigned* EDG = (unsigned*)p;               p += (size_t)NE * 4;
    unsigned short* RNK = (unsigned short*)p;   p += (size_t)NE * 2;
    unsigned short* XB  = (unsigned short*)p;   // 12.8 MB + RB-row slack for gemmB over-read
    int* DEG = (int*)XB;

    // h ping-pongs inside d_out's upper half (bytes 12.8M..25.6M)
    unsigned short* HA = (unsigned short*)d_out + (size_t)NN * DD;

    const int GB  = (NN + RB - 1) / RB;          // 782 MFMA blocks
    const int SB  = (NN + 1023) / 1024;          // 49 scan blocks
    const int EB  = (NE + 255) / 256;            // 2344 edge chunks

    k_sniffzero<<<64, 256, 0, stream>>>((const unsigned*)We, (const unsigned*)adj, FLAGS, DEG);
    k_degprep<<<DD + EB, 256, 0, stream>>>(adj, FLAGS, We, Wu, WeT, WuT, DEG, EDG, RNK);
    k_scan1<<<SB, 1024, 0, stream>>>(DEG, ROWS, SUMS);
    k_scan2<<<1, 64, 0, stream>>>(SUMS, SB);
    k_scan3<<<SB, 1024, 0, stream>>>(SUMS, ROWS);
    k_fill<<<EB * 8, 256, 0, stream>>>(EDG, RNK, ROWS, NBR);

    k_emb<<<GB, 256, 0, stream>>>(X, WeT, be, HA, FLAGS);

    const int GGB = ((NN + 15) / 16) * 4;        // 3125 tiles x 4 slices = 12500 blocks
    for (int it = 0; it < 3; ++it) {
        int last = (it == 2);
        k_gather<<<GGB, 256, 0, stream>>>((const unsigned*)HA, ROWS, NBR, (unsigned*)XB);
        k_gemmB<<<GB, 256, 0, stream>>>(XB, WuT, bu, HA, (float*)d_out, FLAGS, last);
    }
}

// Round 9
// 445.900 us; speedup vs baseline: 14.5092x; 1.0197x over previous
//
#include <hip/hip_runtime.h>
#include <hip/hip_bf16.h>

#define NN 50000
#define NE 600000
#define DD 128
#define RB 64            // rows per MFMA block (4 waves x 16 rows)
#define NSHARD_DIV 6250  // NN/8 node-range per XCD shard

typedef __bf16 bfrag __attribute__((ext_vector_type(8)));
typedef float  ffrag __attribute__((ext_vector_type(4)));
typedef unsigned uintv4 __attribute__((ext_vector_type(4)));   // native vec for nontemporal

__device__ __forceinline__ float bfbits2f(unsigned v) { return __uint_as_float(v << 16); }
__device__ __forceinline__ unsigned f2bfbits(float f) {
    unsigned u = __float_as_uint(f);
    return (u + 0x7FFFu + ((u >> 16) & 1u)) >> 16;   // RNE
}

__device__ __forceinline__ float ld_in(const void* p, int idx, int f32) {
    return f32 ? ((const float*)p)[idx]
               : bfbits2f(((const unsigned short*)p)[idx]);
}

__device__ __forceinline__ void ld_edge(const int* adj, int e, int i64, int& s, int& d) {
    if (i64) { s = adj[4 * e]; d = adj[4 * e + 2]; }
    else     { s = adj[2 * e]; d = adj[2 * e + 1]; }
}

// ---------------- sniffer + DEG zeroing ----------------
__global__ void k_sniffzero(const unsigned* __restrict__ w, const unsigned* __restrict__ adj,
                            int* __restrict__ flags, int* __restrict__ deg) {
    for (int i = blockIdx.x * 256 + threadIdx.x; i < NN; i += 64 * 256) deg[i] = 0;
    if (blockIdx.x != 0) return;
    __shared__ int cnt[2];
    int tid = threadIdx.x;
    if (tid < 2) cnt[tid] = 0;
    __syncthreads();
    int c0 = 0, c1 = 0;
    for (int i = tid; i < 512; i += 256) {
        unsigned e = (w[i] >> 7) & 0xFFu;
        c0 += (e >= 0x60u && e <= 0x85u) ? 1 : 0;       // plausible low-half bf16?
        c1 += (adj[2 * i + 1] == 0u) ? 1 : 0;           // int64 zero high words?
    }
    atomicAdd(&cnt[0], c0);
    atomicAdd(&cnt[1], c1);
    __syncthreads();
    if (tid == 0) {
        flags[0] = (cnt[0] >= 256) ? 0 : 1;   // fp32 inputs?
        flags[1] = (cnt[1] >= 256) ? 1 : 0;   // int64 adjacency?
    }
}

// ---------------- degree (non-returning atomics) + edge compaction + weight prep ----------
__global__ void k_degprep(const int* __restrict__ adj, const int* __restrict__ flags,
                          const void* __restrict__ We, const void* __restrict__ Wu,
                          unsigned short* __restrict__ WeT, unsigned short* __restrict__ WuT,
                          int* __restrict__ deg, unsigned* __restrict__ edg) {
    const int f32 = flags[0];
    if (blockIdx.x < DD) {
        const int k = blockIdx.x, t = threadIdx.x;
        if (t < DD) {
            WeT[t * DD + k] = (unsigned short)f2bfbits(ld_in(We, k * DD + t, f32));
        } else {
            int n = t - DD;
            WuT[n * DD + k] = (unsigned short)f2bfbits(ld_in(Wu, k * DD + n, f32));
        }
        return;
    }
    int e = (blockIdx.x - DD) * 256 + threadIdx.x;
    if (e < NE) {
        int s, d;
        ld_edge(adj, e, flags[1], s, d);
        if ((unsigned)s < NN && (unsigned)d < NN) {
            atomicAdd(&deg[s], 1);
            atomicAdd(&deg[d], 1);
            edg[e] = (unsigned)s | ((unsigned)d << 16);
        } else {
            edg[e] = 0xFFFFFFFFu;             // sentinel: skip in fill
        }
    }
}

// ---------------- hierarchical scan ----------------
__global__ void k_scan1(const int* __restrict__ deg, int* __restrict__ rows,
                        int* __restrict__ sums) {
    __shared__ int sh[1024];
    const int tid = threadIdx.x;
    const int i = blockIdx.x * 1024 + tid;
    sh[tid] = (i < NN) ? deg[i] : 0;
    __syncthreads();
    for (int off = 1; off < 1024; off <<= 1) {
        int t = (tid >= off) ? sh[tid - off] : 0;
        __syncthreads();
        sh[tid] += t;
        __syncthreads();
    }
    if (i < NN) rows[i + 1] = sh[tid];
    if (tid == 1023) sums[blockIdx.x] = sh[1023];
}

__global__ void k_scan2(int* __restrict__ sums, int nb) {
    int t = threadIdx.x;                 // one wave of 64
    int v = (t < nb) ? sums[t] : 0;
    int x = v;
    for (int off = 1; off < 64; off <<= 1) {
        int y = __shfl_up(x, off, 64);
        if (t >= off) x += y;
    }
    if (t < nb) sums[t] = x - v;         // exclusive
}

// rows[i+1] += block offset; cur[i] = rows[i] (cursor start for fill)
__global__ void k_scan3(const int* __restrict__ deg, const int* __restrict__ sums,
                        int* __restrict__ rows, int* __restrict__ cur) {
    int i = blockIdx.x * 1024 + threadIdx.x;
    if (i < NN) {
        int r = rows[i + 1] + sums[blockIdx.x];   // inclusive global
        rows[i + 1] = r;
        cur[i] = r - deg[i];
        if (i == 0) rows[0] = 0;
    }
}

// ---------------- XCD-sharded fill with shard-local atomic cursors ----------------
__launch_bounds__(256)
__global__ void k_fill(const unsigned* __restrict__ edg, const int* __restrict__ flags,
                       int* __restrict__ cur, unsigned short* __restrict__ nbr) {
    const int shard = blockIdx.x & 7;
    const int e = (blockIdx.x >> 3) * 256 + threadIdx.x;
    if (e >= NE) return;
    unsigned v = edg[e];
    if (v == 0xFFFFFFFFu) return;
    int s = v & 0xFFFFu, d = v >> 16;
    if (s / NSHARD_DIV == shard) nbr[atomicAdd(&cur[s], 1)] = (unsigned short)d;
    if (d / NSHARD_DIV == shard) nbr[atomicAdd(&cur[d], 1)] = (unsigned short)s;
}

// ---------------- MFMA core ----------------
__device__ __forceinline__ void mfma_core(const unsigned short* sA, const unsigned short* sWT,
                                          int wave, int lane, ffrag acc[8]) {
    const int m = lane & 15;
    const int quad = lane >> 4;
#pragma unroll
    for (int ks = 0; ks < 4; ks++) {
        const int k0 = ks * 32 + quad * 8;
        bfrag af = *(const bfrag*)&sA[(wave * 16 + m) * DD + k0];
#pragma unroll
        for (int ct = 0; ct < 8; ct++) {
            bfrag bf_ = *(const bfrag*)&sWT[(ct * 16 + m) * DD + k0];
            acc[ct] = __builtin_amdgcn_mfma_f32_16x16x32_bf16(af, bf_, acc[ct], 0, 0, 0);
        }
    }
}

// ---------------- GEMM 1: h0 = relu(X @ W_emb + b) -> bf16 HA ----------------
__launch_bounds__(256, 3)
__global__ void k_emb(const void* __restrict__ Xp, const unsigned short* __restrict__ WTg,
                      const void* __restrict__ Bp, unsigned short* __restrict__ Hout,
                      const int* __restrict__ flags) {
    __shared__ __align__(16) unsigned short sWT[DD * DD];  // 32 KB
    __shared__ __align__(16) unsigned short sA[RB * DD];   // 16 KB
    const int tid  = threadIdx.x;
    const int wave = tid >> 6;
    const int lane = tid & 63;
    const int f32  = flags[0];
    const int rowbase = blockIdx.x * RB + wave * 16;

    for (int i = tid; i < 2048; i += 256)
        ((uintv4*)sWT)[i] = ((const uintv4*)WTg)[i];

#pragma unroll 4
    for (int r = 0; r < 16; r++) {
        int row = rowbase + r;
        unsigned packed = 0;
        if (row < NN) {
            if (f32) {
                float2 v = ((const float2*)Xp)[row * 64 + lane];
                packed = f2bfbits(v.x) | (f2bfbits(v.y) << 16);
            } else {
                packed = ((const unsigned*)Xp)[row * 64 + lane];
            }
        }
        ((unsigned*)sA)[(wave * 16 + r) * 64 + lane] = packed;
    }
    __syncthreads();

    ffrag acc[8];
#pragma unroll
    for (int i = 0; i < 8; i++) acc[i] = (ffrag)(0.0f);
    mfma_core(sA, sWT, wave, lane, acc);

    const int m = lane & 15;
    const int quad = lane >> 4;
#pragma unroll
    for (int ct = 0; ct < 8; ct++) {
        int col = ct * 16 + m;
        float bb = ld_in(Bp, col, f32);
#pragma unroll
        for (int reg = 0; reg < 4; reg++) {
            int row = rowbase + quad * 4 + reg;
            if (row < NN) {
                float z = fmaxf(acc[ct][reg] + bb, 0.0f);
                Hout[row * DD + col] = (unsigned short)f2bfbits(z);
            }
        }
    }
}

// ---------------- gather: full-row, unroll-16 for max MLP ----------------
__launch_bounds__(256)
__global__ void k_gather(const unsigned* __restrict__ H32, const int* __restrict__ rows,
                         const unsigned short* __restrict__ nbr,
                         unsigned* __restrict__ XB32) {
    const int row  = (blockIdx.x * 256 + threadIdx.x) >> 6;
    const int lane = threadIdx.x & 63;
    if (row >= NN) return;
    unsigned selfv = H32[row * 64 + lane];
    float ax = bfbits2f(selfv & 0xFFFFu);
    float ay = bfbits2f(selfv >> 16);
    const int st = rows[row], en = rows[row + 1];
    int j = st;
    for (; j + 16 <= en; j += 16) {
        int n[16];
#pragma unroll
        for (int t = 0; t < 16; t++) n[t] = nbr[j + t];
        unsigned v[16];
#pragma unroll
        for (int t = 0; t < 16; t++) v[t] = H32[n[t] * 64 + lane];
#pragma unroll
        for (int t = 0; t < 16; t++) {
            ax += bfbits2f(v[t] & 0xFFFFu);
            ay += bfbits2f(v[t] >> 16);
        }
    }
    for (; j + 4 <= en; j += 4) {
        int n0 = nbr[j], n1 = nbr[j + 1], n2 = nbr[j + 2], n3 = nbr[j + 3];
        unsigned v0 = H32[n0 * 64 + lane];
        unsigned v1 = H32[n1 * 64 + lane];
        unsigned v2 = H32[n2 * 64 + lane];
        unsigned v3 = H32[n3 * 64 + lane];
        ax += (bfbits2f(v0 & 0xFFFFu) + bfbits2f(v1 & 0xFFFFu)) +
              (bfbits2f(v2 & 0xFFFFu) + bfbits2f(v3 & 0xFFFFu));
        ay += (bfbits2f(v0 >> 16) + bfbits2f(v1 >> 16)) +
              (bfbits2f(v2 >> 16) + bfbits2f(v3 >> 16));
    }
    for (; j < en; ++j) {
        unsigned v = H32[(int)nbr[j] * 64 + lane];
        ax += bfbits2f(v & 0xFFFFu);
        ay += bfbits2f(v >> 16);
    }
    float inv = 1.0f / (float)(en - st + 1);
    unsigned packed = f2bfbits(ax * inv) | (f2bfbits(ay * inv) << 16);
    __builtin_nontemporal_store(packed, &XB32[row * 64 + lane]);  // don't evict h from L2
}

// ---------------- GEMM 2: h_new = sigmoid(XB @ W_upd + b) ----------------
__launch_bounds__(256, 3)
__global__ void k_gemmB(const unsigned short* __restrict__ XB,
                        const unsigned short* __restrict__ WTg, const void* __restrict__ Bp,
                        unsigned short* __restrict__ HoutBf, float* __restrict__ HoutF,
                        const int* __restrict__ flags, int last) {
    __shared__ __align__(16) unsigned short sWT[DD * DD];  // 32 KB
    __shared__ __align__(16) unsigned short sA[RB * DD];   // 16 KB
    const int tid  = threadIdx.x;
    const int wave = tid >> 6;
    const int lane = tid & 63;
    const int f32  = flags[0];
    const int rowbase = blockIdx.x * RB + wave * 16;

    for (int i = tid; i < 2048; i += 256)
        ((uintv4*)sWT)[i] = ((const uintv4*)WTg)[i];

    const uintv4* src = (const uintv4*)(XB + (size_t)blockIdx.x * RB * DD);
#pragma unroll
    for (int i = tid; i < 1024; i += 256)
        ((uintv4*)sA)[i] = __builtin_nontemporal_load(&src[i]);   // single-use stream
    __syncthreads();

    ffrag acc[8];
#pragma unroll
    for (int i = 0; i < 8; i++) acc[i] = (ffrag)(0.0f);
    mfma_core(sA, sWT, wave, lane, acc);

    const int m = lane & 15;
    const int quad = lane >> 4;
#pragma unroll
    for (int ct = 0; ct < 8; ct++) {
        int col = ct * 16 + m;
        float bb = ld_in(Bp, col, f32);
#pragma unroll
        for (int reg = 0; reg < 4; reg++) {
            int row = rowbase + quad * 4 + reg;
            if (row < NN) {
                float s = 1.0f / (1.0f + __expf(-(acc[ct][reg] + bb)));
                if (!last) {
                    HoutBf[row * DD + col] = (unsigned short)f2bfbits(s);
                } else if (f32) {
                    HoutF[row * DD + col] = s;
                } else {
                    ((unsigned short*)HoutF)[row * DD + col] = (unsigned short)f2bfbits(s);
                }
            }
        }
    }
}

extern "C" void kernel_launch(void* const* d_in, const int* in_sizes, int n_in,
                              void* d_out, int out_size, void* d_ws, size_t ws_size,
                              hipStream_t stream) {
    const void* X  = d_in[0];
    const void* We = d_in[1];
    const void* be = d_in[2];
    const void* Wu = d_in[3];
    const void* bu = d_in[4];
    const int* adj = (const int*)d_in[5];

    // ws: FLAGS | ROWS | SUMS | NBR(2.4M) | WeT | WuT | EDG(2.4M) | CUR(200K) | XB(12.8M+slack)
    // DEG aliases XB (dead after scan3, before first gather). Total ~18.5 MB.
    char* p = (char*)d_ws;
    int* FLAGS = (int*)p;                       p += 256;
    int* ROWS  = (int*)p;                       p += ((NN + 1) * 4 + 252) / 256 * 256;
    int* SUMS  = (int*)p;                       p += 256;
    unsigned short* NBR = (unsigned short*)p;   p += (size_t)2 * NE * 2;
    unsigned short* WeT = (unsigned short*)p;   p += DD * DD * 2;
    unsigned short* WuT = (unsigned short*)p;   p += DD * DD * 2;
    unsigned* EDG = (unsigned*)p;               p += (size_t)NE * 4;
    int* CUR = (int*)p;                         p += ((NN * 4 + 255) / 256) * 256;
    unsigned short* XB  = (unsigned short*)p;   // 12.8 MB + RB-row over-read slack
    int* DEG = (int*)XB;

    // h ping-pongs inside d_out's upper half (bytes 12.8M..25.6M)
    unsigned short* HA = (unsigned short*)d_out + (size_t)NN * DD;

    const int GB  = (NN + RB - 1) / RB;          // 782 MFMA blocks
    const int SB  = (NN + 1023) / 1024;          // 49 scan blocks
    const int EB  = (NE + 255) / 256;            // 2344 edge chunks

    k_sniffzero<<<64, 256, 0, stream>>>((const unsigned*)We, (const unsigned*)adj, FLAGS, DEG);
    k_degprep<<<DD + EB, 256, 0, stream>>>(adj, FLAGS, We, Wu, WeT, WuT, DEG, EDG);
    k_scan1<<<SB, 1024, 0, stream>>>(DEG, ROWS, SUMS);
    k_scan2<<<1, 64, 0, stream>>>(SUMS, SB);
    k_scan3<<<SB, 1024, 0, stream>>>(DEG, SUMS, ROWS, CUR);
    k_fill<<<EB * 8, 256, 0, stream>>>(EDG, FLAGS, CUR, NBR);

    k_emb<<<GB, 256, 0, stream>>>(X, WeT, be, HA, FLAGS);

    const int GGB = (NN * 64 + 255) / 256;       // 12500 gather blocks
    for (int it = 0; it < 3; ++it) {
        int last = (it == 2);
        k_gather<<<GGB, 256, 0, stream>>>((const unsigned*)HA, ROWS, NBR, (unsigned*)XB);
        k_gemmB<<<GB, 256, 0, stream>>>(XB, WuT, bu, HA, (float*)d_out, FLAGS, last);
    }
}

// Round 10
// 418.950 us; speedup vs baseline: 15.4425x; 1.0643x over previous
//
#include <hip/hip_runtime.h>
#include <hip/hip_bf16.h>

#define NN 50000
#define NE 600000
#define DD 128
#define RB 64            // rows per MFMA block (4 waves x 16 rows)
#define NSHARD_DIV 6250  // NN/8 node-range per XCD shard

typedef __bf16 bfrag __attribute__((ext_vector_type(8)));
typedef float  ffrag __attribute__((ext_vector_type(4)));
typedef unsigned uintv4 __attribute__((ext_vector_type(4)));   // native vec for nontemporal

union frag_cast { uintv4 u4; unsigned u[4]; bfrag b; };

__device__ __forceinline__ float bfbits2f(unsigned v) { return __uint_as_float(v << 16); }
__device__ __forceinline__ unsigned f2bfbits(float f) {
    unsigned u = __float_as_uint(f);
    return (u + 0x7FFFu + ((u >> 16) & 1u)) >> 16;   // RNE
}

__device__ __forceinline__ float ld_in(const void* p, int idx, int f32) {
    return f32 ? ((const float*)p)[idx]
               : bfbits2f(((const unsigned short*)p)[idx]);
}

__device__ __forceinline__ void ld_edge_nt(const int* adj, int e, int i64, int& s, int& d) {
    if (i64) {
        s = __builtin_nontemporal_load(&adj[4 * e]);
        d = __builtin_nontemporal_load(&adj[4 * e + 2]);
    } else {
        s = __builtin_nontemporal_load(&adj[2 * e]);
        d = __builtin_nontemporal_load(&adj[2 * e + 1]);
    }
}

// ---------------- sniffer + DEG zeroing ----------------
__global__ void k_sniffzero(const unsigned* __restrict__ w, const unsigned* __restrict__ adj,
                            int* __restrict__ flags, int* __restrict__ deg) {
    for (int i = blockIdx.x * 256 + threadIdx.x; i < NN; i += 64 * 256) deg[i] = 0;
    if (blockIdx.x != 0) return;
    __shared__ int cnt[2];
    int tid = threadIdx.x;
    if (tid < 2) cnt[tid] = 0;
    __syncthreads();
    int c0 = 0, c1 = 0;
    for (int i = tid; i < 512; i += 256) {
        unsigned e = (w[i] >> 7) & 0xFFu;
        c0 += (e >= 0x60u && e <= 0x85u) ? 1 : 0;       // plausible low-half bf16?
        c1 += (adj[2 * i + 1] == 0u) ? 1 : 0;           // int64 zero high words?
    }
    atomicAdd(&cnt[0], c0);
    atomicAdd(&cnt[1], c1);
    __syncthreads();
    if (tid == 0) {
        flags[0] = (cnt[0] >= 256) ? 0 : 1;   // fp32 inputs?
        flags[1] = (cnt[1] >= 256) ? 1 : 0;   // int64 adjacency?
    }
}

// ---------------- degree (non-returning atomics) + edge compaction + weight prep ----------
__global__ void k_degprep(const int* __restrict__ adj, const int* __restrict__ flags,
                          const void* __restrict__ We, const void* __restrict__ Wu,
                          unsigned short* __restrict__ WeT, unsigned short* __restrict__ WuT,
                          int* __restrict__ deg, unsigned* __restrict__ edg) {
    const int f32 = flags[0];
    if (blockIdx.x < DD) {
        const int k = blockIdx.x, t = threadIdx.x;
        if (t < DD) {
            WeT[t * DD + k] = (unsigned short)f2bfbits(ld_in(We, k * DD + t, f32));
        } else {
            int n = t - DD;
            WuT[n * DD + k] = (unsigned short)f2bfbits(ld_in(Wu, k * DD + n, f32));
        }
        return;
    }
    int e = (blockIdx.x - DD) * 256 + threadIdx.x;
    if (e < NE) {
        int s, d;
        ld_edge_nt(adj, e, flags[1], s, d);
        if ((unsigned)s < NN && (unsigned)d < NN) {
            atomicAdd(&deg[s], 1);
            atomicAdd(&deg[d], 1);
            edg[e] = (unsigned)s | ((unsigned)d << 16);
        } else {
            edg[e] = 0xFFFFFFFFu;             // sentinel: skip in fill
        }
    }
}

// ---------------- hierarchical scan ----------------
__global__ void k_scan1(const int* __restrict__ deg, int* __restrict__ rows,
                        int* __restrict__ sums) {
    __shared__ int sh[1024];
    const int tid = threadIdx.x;
    const int i = blockIdx.x * 1024 + tid;
    sh[tid] = (i < NN) ? deg[i] : 0;
    __syncthreads();
    for (int off = 1; off < 1024; off <<= 1) {
        int t = (tid >= off) ? sh[tid - off] : 0;
        __syncthreads();
        sh[tid] += t;
        __syncthreads();
    }
    if (i < NN) rows[i + 1] = sh[tid];
    if (tid == 1023) sums[blockIdx.x] = sh[1023];
}

__global__ void k_scan2(int* __restrict__ sums, int nb) {
    int t = threadIdx.x;                 // one wave of 64
    int v = (t < nb) ? sums[t] : 0;
    int x = v;
    for (int off = 1; off < 64; off <<= 1) {
        int y = __shfl_up(x, off, 64);
        if (t >= off) x += y;
    }
    if (t < nb) sums[t] = x - v;         // exclusive
}

__global__ void k_scan3(const int* __restrict__ deg, const int* __restrict__ sums,
                        int* __restrict__ rows, int* __restrict__ cur) {
    int i = blockIdx.x * 1024 + threadIdx.x;
    if (i < NN) {
        int r = rows[i + 1] + sums[blockIdx.x];   // inclusive global
        rows[i + 1] = r;
        cur[i] = r - deg[i];
        if (i == 0) rows[0] = 0;
    }
}

// ---------------- XCD-sharded fill, nontemporal EDG stream ----------------
// NT read keeps the EDG stream from evicting dirty NBR/CUR lines out of L2.
__launch_bounds__(256)
__global__ void k_fill(const unsigned* __restrict__ edg, const int* __restrict__ flags,
                       int* __restrict__ cur, unsigned short* __restrict__ nbr) {
    const int shard = blockIdx.x & 7;
    const int e = (blockIdx.x >> 3) * 256 + threadIdx.x;
    if (e >= NE) return;
    unsigned v = __builtin_nontemporal_load(&edg[e]);
    if (v == 0xFFFFFFFFu) return;
    int s = v & 0xFFFFu, d = v >> 16;
    if (s / NSHARD_DIV == shard) nbr[atomicAdd(&cur[s], 1)] = (unsigned short)d;
    if (d / NSHARD_DIV == shard) nbr[atomicAdd(&cur[d], 1)] = (unsigned short)s;
}

// ---------------- MFMA core: A-fragments from registers, B from LDS ----------------
__device__ __forceinline__ void mfma_rows(const bfrag af[4], const unsigned short* sWT,
                                          int m, int quad, ffrag acc[8]) {
#pragma unroll
    for (int ks = 0; ks < 4; ks++) {
        const int k0 = ks * 32 + quad * 8;
#pragma unroll
        for (int ct = 0; ct < 8; ct++) {
            bfrag bf_ = *(const bfrag*)&sWT[(ct * 16 + m) * DD + k0];
            acc[ct] = __builtin_amdgcn_mfma_f32_16x16x32_bf16(af[ks], bf_, acc[ct], 0, 0, 0);
        }
    }
}

// ---------------- GEMM 1: h0 = relu(X @ W_emb + b) -> bf16 HA ----------------
// A-fragments read directly from global X (fp32->bf16 in-register); LDS = sWT only.
__launch_bounds__(256, 5)
__global__ void k_emb(const void* __restrict__ Xp, const unsigned short* __restrict__ WTg,
                      const void* __restrict__ Bp, unsigned short* __restrict__ Hout,
                      const int* __restrict__ flags) {
    __shared__ __align__(16) unsigned short sWT[DD * DD];  // 32 KB
    const int tid  = threadIdx.x;
    const int wave = tid >> 6;
    const int lane = tid & 63;
    const int f32  = flags[0];
    const int m    = lane & 15;
    const int quad = lane >> 4;
    const int rowbase = blockIdx.x * RB + wave * 16;
    const int row  = rowbase + m;
    const int rc   = (row < NN) ? row : (NN - 1);   // clamp for load; stores guarded

    for (int i = tid; i < 2048; i += 256)
        ((uintv4*)sWT)[i] = ((const uintv4*)WTg)[i];

    bfrag af[4];
    if (f32) {
        const float4* Xf = (const float4*)Xp;
#pragma unroll
        for (int ks = 0; ks < 4; ks++) {
            const int k0 = ks * 32 + quad * 8;
            float4 a0 = Xf[rc * 32 + (k0 >> 2)];
            float4 a1 = Xf[rc * 32 + (k0 >> 2) + 1];
            frag_cast fc;
            fc.u[0] = f2bfbits(a0.x) | (f2bfbits(a0.y) << 16);
            fc.u[1] = f2bfbits(a0.z) | (f2bfbits(a0.w) << 16);
            fc.u[2] = f2bfbits(a1.x) | (f2bfbits(a1.y) << 16);
            fc.u[3] = f2bfbits(a1.z) | (f2bfbits(a1.w) << 16);
            af[ks] = fc.b;
        }
    } else {
        const uintv4* Xv = (const uintv4*)Xp;
#pragma unroll
        for (int ks = 0; ks < 4; ks++) {
            const int k0 = ks * 32 + quad * 8;
            frag_cast fc;
            fc.u4 = Xv[rc * 16 + (k0 >> 3)];
            af[ks] = fc.b;
        }
    }
    __syncthreads();

    ffrag acc[8];
#pragma unroll
    for (int i = 0; i < 8; i++) acc[i] = (ffrag)(0.0f);
    mfma_rows(af, sWT, m, quad, acc);

#pragma unroll
    for (int ct = 0; ct < 8; ct++) {
        int col = ct * 16 + m;
        float bb = ld_in(Bp, col, f32);
#pragma unroll
        for (int reg = 0; reg < 4; reg++) {
            int orow = rowbase + quad * 4 + reg;
            if (orow < NN) {
                float z = fmaxf(acc[ct][reg] + bb, 0.0f);
                Hout[orow * DD + col] = (unsigned short)f2bfbits(z);
            }
        }
    }
}

// ---------------- gather: full-row, unroll-16, NT nbr stream + NT XB store ----------------
__launch_bounds__(256)
__global__ void k_gather(const unsigned* __restrict__ H32, const int* __restrict__ rows,
                         const unsigned short* __restrict__ nbr,
                         unsigned* __restrict__ XB32) {
    const int row  = (blockIdx.x * 256 + threadIdx.x) >> 6;
    const int lane = threadIdx.x & 63;
    if (row >= NN) return;
    unsigned selfv = H32[row * 64 + lane];
    float ax = bfbits2f(selfv & 0xFFFFu);
    float ay = bfbits2f(selfv >> 16);
    const int st = rows[row], en = rows[row + 1];
    int j = st;
    for (; j + 16 <= en; j += 16) {
        int n[16];
#pragma unroll
        for (int t = 0; t < 16; t++) n[t] = __builtin_nontemporal_load(&nbr[j + t]);
        unsigned v[16];
#pragma unroll
        for (int t = 0; t < 16; t++) v[t] = H32[n[t] * 64 + lane];
#pragma unroll
        for (int t = 0; t < 16; t++) {
            ax += bfbits2f(v[t] & 0xFFFFu);
            ay += bfbits2f(v[t] >> 16);
        }
    }
    for (; j + 4 <= en; j += 4) {
        int n0 = __builtin_nontemporal_load(&nbr[j]);
        int n1 = __builtin_nontemporal_load(&nbr[j + 1]);
        int n2 = __builtin_nontemporal_load(&nbr[j + 2]);
        int n3 = __builtin_nontemporal_load(&nbr[j + 3]);
        unsigned v0 = H32[n0 * 64 + lane];
        unsigned v1 = H32[n1 * 64 + lane];
        unsigned v2 = H32[n2 * 64 + lane];
        unsigned v3 = H32[n3 * 64 + lane];
        ax += (bfbits2f(v0 & 0xFFFFu) + bfbits2f(v1 & 0xFFFFu)) +
              (bfbits2f(v2 & 0xFFFFu) + bfbits2f(v3 & 0xFFFFu));
        ay += (bfbits2f(v0 >> 16) + bfbits2f(v1 >> 16)) +
              (bfbits2f(v2 >> 16) + bfbits2f(v3 >> 16));
    }
    for (; j < en; ++j) {
        unsigned v = H32[(int)__builtin_nontemporal_load(&nbr[j]) * 64 + lane];
        ax += bfbits2f(v & 0xFFFFu);
        ay += bfbits2f(v >> 16);
    }
    float inv = 1.0f / (float)(en - st + 1);
    unsigned packed = f2bfbits(ax * inv) | (f2bfbits(ay * inv) << 16);
    __builtin_nontemporal_store(packed, &XB32[row * 64 + lane]);  // don't evict h from L2
}

// ---------------- GEMM 2: h_new = sigmoid(XB @ W_upd + b) ----------------
// A-fragments NT-loaded directly from XB (over-read covered by ws slack); LDS = sWT only.
__launch_bounds__(256, 5)
__global__ void k_gemmB(const unsigned short* __restrict__ XB,
                        const unsigned short* __restrict__ WTg, const void* __restrict__ Bp,
                        unsigned short* __restrict__ HoutBf, float* __restrict__ HoutF,
                        const int* __restrict__ flags, int last) {
    __shared__ __align__(16) unsigned short sWT[DD * DD];  // 32 KB
    const int tid  = threadIdx.x;
    const int wave = tid >> 6;
    const int lane = tid & 63;
    const int f32  = flags[0];
    const int m    = lane & 15;
    const int quad = lane >> 4;
    const int rowbase = blockIdx.x * RB + wave * 16;
    const int row  = rowbase + m;

    for (int i = tid; i < 2048; i += 256)
        ((uintv4*)sWT)[i] = ((const uintv4*)WTg)[i];

    bfrag af[4];
    const uintv4* Xv = (const uintv4*)XB;
#pragma unroll
    for (int ks = 0; ks < 4; ks++) {
        const int k0 = ks * 32 + quad * 8;
        frag_cast fc;
        fc.u4 = __builtin_nontemporal_load(&Xv[row * 16 + (k0 >> 3)]);  // single-use stream
        af[ks] = fc.b;
    }
    __syncthreads();

    ffrag acc[8];
#pragma unroll
    for (int i = 0; i < 8; i++) acc[i] = (ffrag)(0.0f);
    mfma_rows(af, sWT, m, quad, acc);

#pragma unroll
    for (int ct = 0; ct < 8; ct++) {
        int col = ct * 16 + m;
        float bb = ld_in(Bp, col, f32);
#pragma unroll
        for (int reg = 0; reg < 4; reg++) {
            int orow = rowbase + quad * 4 + reg;
            if (orow < NN) {
                float s = 1.0f / (1.0f + __expf(-(acc[ct][reg] + bb)));
                if (!last) {
                    HoutBf[orow * DD + col] = (unsigned short)f2bfbits(s);
                } else if (f32) {
                    HoutF[orow * DD + col] = s;
                } else {
                    ((unsigned short*)HoutF)[orow * DD + col] = (unsigned short)f2bfbits(s);
                }
            }
        }
    }
}

extern "C" void kernel_launch(void* const* d_in, const int* in_sizes, int n_in,
                              void* d_out, int out_size, void* d_ws, size_t ws_size,
                              hipStream_t stream) {
    const void* X  = d_in[0];
    const void* We = d_in[1];
    const void* be = d_in[2];
    const void* Wu = d_in[3];
    const void* bu = d_in[4];
    const int* adj = (const int*)d_in[5];

    // ws: FLAGS | ROWS | SUMS | NBR(2.4M) | WeT | WuT | EDG(2.4M) | CUR(200K) | XB(12.8M+slack)
    // DEG aliases XB (dead after scan3, before first gather). Total ~18.6 MB (<26 MB proven).
    char* p = (char*)d_ws;
    int* FLAGS = (int*)p;                       p += 256;
    int* ROWS  = (int*)p;                       p += ((NN + 1) * 4 + 252) / 256 * 256;
    int* SUMS  = (int*)p;                       p += 256;
    unsigned short* NBR = (unsigned short*)p;   p += (size_t)2 * NE * 2;
    unsigned short* WeT = (unsigned short*)p;   p += DD * DD * 2;
    unsigned short* WuT = (unsigned short*)p;   p += DD * DD * 2;
    unsigned* EDG = (unsigned*)p;               p += (size_t)NE * 4;
    int* CUR = (int*)p;                         p += ((NN * 4 + 255) / 256) * 256;
    unsigned short* XB  = (unsigned short*)p;   // 12.8 MB + 16 KB over-read slack (RB rows)
    int* DEG = (int*)XB;

    // h ping-pongs inside d_out's upper half (bytes 12.8M..25.6M)
    unsigned short* HA = (unsigned short*)d_out + (size_t)NN * DD;

    const int GB  = (NN + RB - 1) / RB;          // 782 MFMA blocks
    const int SB  = (NN + 1023) / 1024;          // 49 scan blocks
    const int EB  = (NE + 255) / 256;            // 2344 edge chunks

    k_sniffzero<<<64, 256, 0, stream>>>((const unsigned*)We, (const unsigned*)adj, FLAGS, DEG);
    k_degprep<<<DD + EB, 256, 0, stream>>>(adj, FLAGS, We, Wu, WeT, WuT, DEG, EDG);
    k_scan1<<<SB, 1024, 0, stream>>>(DEG, ROWS, SUMS);
    k_scan2<<<1, 64, 0, stream>>>(SUMS, SB);
    k_scan3<<<SB, 1024, 0, stream>>>(DEG, SUMS, ROWS, CUR);
    k_fill<<<EB * 8, 256, 0, stream>>>(EDG, FLAGS, CUR, NBR);

    k_emb<<<GB, 256, 0, stream>>>(X, WeT, be, HA, FLAGS);

    const int GGB = (NN * 64 + 255) / 256;       // 12500 gather blocks
    for (int it = 0; it < 3; ++it) {
        int last = (it == 2);
        k_gather<<<GGB, 256, 0, stream>>>((const unsigned*)HA, ROWS, NBR, (unsigned*)XB);
        k_gemmB<<<GB, 256, 0, stream>>>(XB, WuT, bu, HA, (float*)d_out, FLAGS, last);
    }
}